// Round 3
// baseline (227.730 us; speedup 1.0000x reference)
//
#include <hip/hip_runtime.h>
#include <stdint.h>

// ---------- types / helpers ----------
typedef short bf16x8 __attribute__((ext_vector_type(8)));
typedef float f32x4 __attribute__((ext_vector_type(4)));

#define MFMA_BF16(a, b, c) __builtin_amdgcn_mfma_f32_16x16x32_bf16((a), (b), (c), 0, 0, 0)

__device__ __forceinline__ short f2bf(float x) {
  union { float f; uint32_t u; } v; v.f = x;
  uint32_t r = (v.u + 0x7FFFu + ((v.u >> 16) & 1u)) >> 16;  // RNE
  return (short)r;
}
__device__ __forceinline__ uint32_t rnd_bf_hi(float x) {  // rounded bits, bf16 in high half
  union { float f; uint32_t u; } v; v.f = x;
  return v.u + 0x7FFFu + ((v.u >> 16) & 1u);
}
__device__ __forceinline__ uint32_t pack2bf(float a, float b) {
  // D = [bf16(b) : bf16(a)]  via byte-select
  return __builtin_amdgcn_perm(rnd_bf_hi(b), rnd_bf_hi(a), 0x07060302);
}
__device__ __forceinline__ float bfbits2f(uint32_t b16) {
  union { uint32_t u; float f; } v; v.u = b16 << 16; return v.f;
}
__device__ __forceinline__ float fexp2(float x) {
#if __has_builtin(__builtin_amdgcn_exp2f)
  return __builtin_amdgcn_exp2f(x);
#else
  return __expf(x * 0.6931471805599453f);
#endif
}
__device__ __forceinline__ void async16(const void* g, void* l) {
  __builtin_amdgcn_global_load_lds(
      (const __attribute__((address_space(1))) uint32_t*)g,
      (__attribute__((address_space(3))) uint32_t*)l, 16, 0, 0);
}

// ---------- fused fp32 -> bf16 casts (x + 4 weights, one launch) ----------
__global__ __launch_bounds__(256) void cvt_all(
    const float* __restrict__ x, const float* __restrict__ Wq,
    const float* __restrict__ Wk, const float* __restrict__ Wv,
    const float* __restrict__ Wo,
    short* __restrict__ xb, short* __restrict__ Wqb, short* __restrict__ Wkb,
    short* __restrict__ Wvb, short* __restrict__ Wob) {
  const int bid = blockIdx.x;
  const float* src; short* dst; int idx;
  if (bid < 4096) {
    src = x; dst = xb; idx = (bid << 8) + threadIdx.x;
  } else {
    const int r = bid - 4096;
    const int z = r >> 10;
    src = (z == 0) ? Wq : (z == 1) ? Wk : (z == 2) ? Wv : Wo;
    dst = (z == 0) ? Wqb : (z == 1) ? Wkb : (z == 2) ? Wvb : Wob;
    idx = ((r & 1023) << 8) + threadIdx.x;
  }
  float4 v = ((const float4*)src)[idx];
  short4 o;
  o.x = f2bf(v.x); o.y = f2bf(v.y); o.z = f2bf(v.z); o.w = f2bf(v.w);
  ((short4*)dst)[idx] = o;
}

// ---------- gates: context = x[b,0,:] @ Wq^T + bq (fp32, exact path) ----------
__global__ __launch_bounds__(256) void gates_ctx(const float* __restrict__ x,
                                                 const float* __restrict__ Wq,
                                                 const float* __restrict__ bq,
                                                 float* __restrict__ ctx) {
  const int b = blockIdx.x;         // 4
  const int n0 = blockIdx.y << 6;   // 16 blocks of 64 rows
  __shared__ float xs[1024];
  const int tid = threadIdx.x;
  for (int i = tid; i < 1024; i += 256) xs[i] = x[b * 1048576 + i];  // x[b,0,:]
  __syncthreads();
  const int w = tid >> 6, lane = tid & 63;
  const float4* xv4 = (const float4*)xs;
  for (int rr = 0; rr < 16; ++rr) {
    const int n = n0 + (w << 4) + rr;
    const float4* wrow = (const float4*)(Wq + n * 1024);
    float p = 0.f;
#pragma unroll
    for (int c2 = 0; c2 < 4; ++c2) {
      float4 wv = wrow[lane + (c2 << 6)];
      float4 xv = xv4[lane + (c2 << 6)];
      p += xv.x * wv.x + xv.y * wv.y + xv.z * wv.z + xv.w * wv.w;
    }
#pragma unroll
    for (int off = 32; off; off >>= 1) p += __shfl_xor(p, off);
    if (lane == 0) ctx[b * 1024 + n] = p + bq[n];
  }
}

// ---------- gates finisher: c, scale, u ----------
__global__ __launch_bounds__(256) void gates_fin(const float* __restrict__ ctx,
                                                 const float* __restrict__ Wg1,
                                                 const float* __restrict__ bg1,
                                                 const float* __restrict__ Wg2,
                                                 const float* __restrict__ bg2,
                                                 float* __restrict__ gates,
                                                 float* __restrict__ u_out) {
  __shared__ float red[16];
  const int tid = threadIdx.x, w = tid >> 6, lane = tid & 63;
  for (int b = 0; b < 4; ++b) {
    float4 cv = ((const float4*)(ctx + b * 1024))[tid];
    float4 w1 = ((const float4*)Wg1)[tid];
    float4 w2 = ((const float4*)Wg2)[tid];
    float p1 = cv.x * w1.x + cv.y * w1.y + cv.z * w1.z + cv.w * w1.w;
    float p2 = cv.x * w2.x + cv.y * w2.y + cv.z * w2.z + cv.w * w2.w;
#pragma unroll
    for (int off = 32; off; off >>= 1) { p1 += __shfl_xor(p1, off); p2 += __shfl_xor(p2, off); }
    if (lane == 0) { red[w] = p1; red[8 + w] = p2; }
    __syncthreads();
    if (tid == 0) {
      float g1 = red[0] + red[1] + red[2] + red[3] + bg1[0];
      float g2 = red[8] + red[9] + red[10] + red[11] + bg2[0];
      float q1 = 1.f / (1.f + expf(-g1));
      float q2 = 1.f / (1.f + expf(-g2));
      float c = fminf(fmaxf(q1 * q2, 1e-8f), 1.0f);
      gates[b * 2 + 0] = c;
      gates[b * 2 + 1] = (c < 0.3f ? c : 1.0f) * 0.125f;  // 1/(sqrt(64)*tau)
      u_out[b] = 1.0f - c;
    }
    __syncthreads();
  }
}

// ---------- QKV projection GEMM, double-buffered LDS (1 barrier/iter) ----------
// C[m,n] = sum_k xb[m,k]*W[n,k] + bias[n];  z=0:Q(scaled)  z=1:K  z=2:V^T [BH][64][T]
__global__ __launch_bounds__(256) void gemm_qkv(
    const short* __restrict__ xb,
    const short* __restrict__ Wqb, const short* __restrict__ Wkb, const short* __restrict__ Wvb,
    const float* __restrict__ bq, const float* __restrict__ bk, const float* __restrict__ bv,
    const float* __restrict__ gat,
    short* __restrict__ Qh, short* __restrict__ Kh, short* __restrict__ Vt) {
  const int z = blockIdx.z;
  const short* W = (z == 0) ? Wqb : (z == 1) ? Wkb : Wvb;
  const float* bias = (z == 0) ? bq : (z == 1) ? bk : bv;

  const int m0 = blockIdx.x << 7;
  const int n0 = blockIdx.y << 7;
  const int tid = threadIdx.x;
  const int w = tid >> 6, lane = tid & 63;
  const int m15 = lane & 15, quad = lane >> 4;
  const int wr = w >> 1, wc = w & 1;

  // Q pre-scale: scale * log2(e), block-uniform (128 rows never cross a batch)
  const float qsc = (z == 0) ? gat[(m0 >> 10) * 2 + 1] * 1.4426950408889634f : 1.0f;

  __shared__ short As[2][4096];
  __shared__ short Bs[2][4096];

  f32x4 acc[4][4];
#pragma unroll
  for (int i = 0; i < 4; ++i)
#pragma unroll
    for (int j = 0; j < 4; ++j) { f32x4 zz = {0.f, 0.f, 0.f, 0.f}; acc[i][j] = zz; }

  const int srow = (w << 5) + (lane >> 2);    // lane-linear: l0 = w*1024 + lane*8
  const int scol = (lane & 3) << 3;
  const int l0 = srow * 32 + scol;
  const short* gA = xb + (m0 + srow) * 1024 + scol;
  const short* gB = W + (n0 + srow) * 1024 + scol;

#define GSTAGE(kt, bi)                                              \
  do {                                                              \
    const short* A_ = gA + ((kt) << 5);                             \
    const short* B_ = gB + ((kt) << 5);                             \
    async16(A_, &As[bi][l0]); async16(A_ + 16384, &As[bi][l0 + 512]);\
    async16(B_, &Bs[bi][l0]); async16(B_ + 16384, &Bs[bi][l0 + 512]);\
  } while (0)

  GSTAGE(0, 0);
  for (int kt = 0; kt < 32; ++kt) {
    __syncthreads();                 // drains GSTAGE(kt); protects buffer reuse
    if (kt < 31) GSTAGE(kt + 1, (kt + 1) & 1);
    const int cur = kt & 1;
    bf16x8 a[4], b[4];
#pragma unroll
    for (int i = 0; i < 4; ++i)
      a[i] = *(const bf16x8*)(&As[cur][((wr << 6) + (i << 4) + m15) * 32 + (quad << 3)]);
#pragma unroll
    for (int j = 0; j < 4; ++j)
      b[j] = *(const bf16x8*)(&Bs[cur][((wc << 6) + (j << 4) + m15) * 32 + (quad << 3)]);
#pragma unroll
    for (int i = 0; i < 4; ++i)
#pragma unroll
      for (int j = 0; j < 4; ++j)
        acc[i][j] = MFMA_BF16(a[i], b[j], acc[i][j]);
  }
#undef GSTAGE

  if (z == 2) {
    // V: per-wave 64x64 transpose in LDS (XOR-swizzled), coalesced 16B stores
    __syncthreads();  // all waves done reading staging LDS
    short* Ts = (w < 2) ? &As[w][0] : &Bs[w - 2][0];  // 4096 shorts per wave
    const int batch = m0 >> 10;
    const int tb0 = (m0 & 1023) + (wr << 6);
    const int h = (n0 >> 6) + wc;
#pragma unroll
    for (int j = 0; j < 4; ++j) {
      const int dkl = (j << 4) + m15;
      const float bb_ = bias[n0 + (wc << 6) + dkl];
#pragma unroll
      for (int i = 0; i < 4; ++i) {
        // t_local = (i<<4)+(quad<<2)+r ; block = t>>3, within = t&7
        uint2 pk;
        pk.x = pack2bf(acc[i][j][0] + bb_, acc[i][j][1] + bb_);
        pk.y = pack2bf(acc[i][j][2] + bb_, acc[i][j][3] + bb_);
        const int blk = (i << 1) + (quad >> 1);
        const int addr = (dkl << 6) + ((blk ^ (dkl & 7)) << 3) + ((quad & 1) << 2);
        *(uint2*)&Ts[addr] = pk;
      }
    }
    __syncthreads();  // wave-local really, but cheap & safe
    const int tb = lane & 7, dr = lane >> 3;
#pragma unroll
    for (int it = 0; it < 8; ++it) {
      const int dkl = dr + (it << 3);
      const int addr = (dkl << 6) + ((tb ^ (dkl & 7)) << 3);
      uint4 vv = *(const uint4*)&Ts[addr];
      *(uint4*)(Vt + ((((batch << 4) + h) << 6) + dkl) * 1024 + tb0 + (tb << 3)) = vv;
    }
  } else {
#pragma unroll
    for (int j = 0; j < 4; ++j) {
      const int n = n0 + (wc << 6) + (j << 4) + m15;
      const float bb_ = bias[n];
      const int h = n >> 6, dk = n & 63;
#pragma unroll
      for (int i = 0; i < 4; ++i) {
        const int mb = m0 + (wr << 6) + (i << 4) + (quad << 2);
#pragma unroll
        for (int r = 0; r < 4; ++r) {
          const int m = mb + r;
          const int batch = m >> 10, t = m & 1023;
          const short o = f2bf((acc[i][j][r] + bb_) * qsc);
          if (z == 1) Kh[((batch * 16 + h) * 1024 + t) * 64 + dk] = o;
          else        Qh[((batch * 16 + h) * 1024 + t) * 64 + dk] = o;
        }
      }
    }
  }
}

// ---------- output projection GEMM: 64x128 tiles, dbuf, fp32 epilogue ----------
__global__ __launch_bounds__(256) void gemm_out(const short* __restrict__ Ab,
                                                const short* __restrict__ Wo,
                                                const float* __restrict__ bo,
                                                float* __restrict__ Cout) {
  const int m0 = blockIdx.x << 6;
  const int n0 = blockIdx.y << 7;
  const int tid = threadIdx.x;
  const int w = tid >> 6, lane = tid & 63;
  const int m15 = lane & 15, quad = lane >> 4;
  const int wr = w >> 1, wc = w & 1;

  __shared__ short As[2][2048];   // 64 x 32
  __shared__ short Bs[2][4096];   // 128 x 32

  f32x4 acc[2][4];
#pragma unroll
  for (int i = 0; i < 2; ++i)
#pragma unroll
    for (int j = 0; j < 4; ++j) { f32x4 zz = {0.f, 0.f, 0.f, 0.f}; acc[i][j] = zz; }

  const int arow = tid >> 2;                 // 64 rows, lane-linear lA = tid*8
  const int acol = (tid & 3) << 3;
  const int lA = arow * 32 + acol;
  const short* gA = Ab + (m0 + arow) * 1024 + acol;

  const int srow = (w << 5) + (lane >> 2);   // B: same as qkv
  const int scol = (lane & 3) << 3;
  const int lB = srow * 32 + scol;
  const short* gB = Wo + (n0 + srow) * 1024 + scol;

#define OSTAGE(kt, bi)                                              \
  do {                                                              \
    const short* A_ = gA + ((kt) << 5);                             \
    const short* B_ = gB + ((kt) << 5);                             \
    async16(A_, &As[bi][lA]);                                       \
    async16(B_, &Bs[bi][lB]); async16(B_ + 16384, &Bs[bi][lB + 512]);\
  } while (0)

  OSTAGE(0, 0);
  for (int kt = 0; kt < 32; ++kt) {
    __syncthreads();
    if (kt < 31) OSTAGE(kt + 1, (kt + 1) & 1);
    const int cur = kt & 1;
    bf16x8 a[2], b[4];
#pragma unroll
    for (int i = 0; i < 2; ++i)
      a[i] = *(const bf16x8*)(&As[cur][((wr << 5) + (i << 4) + m15) * 32 + (quad << 3)]);
#pragma unroll
    for (int j = 0; j < 4; ++j)
      b[j] = *(const bf16x8*)(&Bs[cur][((wc << 6) + (j << 4) + m15) * 32 + (quad << 3)]);
#pragma unroll
    for (int i = 0; i < 2; ++i)
#pragma unroll
      for (int j = 0; j < 4; ++j)
        acc[i][j] = MFMA_BF16(a[i], b[j], acc[i][j]);
  }
#undef OSTAGE

#pragma unroll
  for (int j = 0; j < 4; ++j) {
    const int n = n0 + (wc << 6) + (j << 4) + m15;
    const float bb_ = bo[n];
#pragma unroll
    for (int i = 0; i < 2; ++i) {
      const int mb = m0 + (wr << 5) + (i << 4) + (quad << 2);
#pragma unroll
      for (int r = 0; r < 4; ++r)
        Cout[(mb + r) * 1024 + n] = acc[i][j][r] + bb_;
    }
  }
}

// ---------- meanV over keys: meanV[bh][d] = mean_t Vt[bh][d][t] ----------
__global__ __launch_bounds__(256) void meanv_k(const short* __restrict__ Vt,
                                               float* __restrict__ meanV) {
  const int bh = blockIdx.x;
  const int tid = threadIdx.x;
  const int d = tid >> 2, part = tid & 3;
  const short* row = Vt + bh * 65536 + d * 1024 + part * 256;
  float s = 0.f;
#pragma unroll 4
  for (int i = 0; i < 64; ++i) {
    uint2 v = *(const uint2*)(row + i * 4);
    s += bfbits2f(v.x & 0xffffu) + bfbits2f(v.x >> 16) +
         bfbits2f(v.y & 0xffffu) + bfbits2f(v.y >> 16);
  }
  s += __shfl_xor(s, 1);
  s += __shfl_xor(s, 2);
  if (part == 0) meanV[bh * 64 + d] = s * (1.0f / 1024.0f);
}

// ---------- flash attention, transposed-S formulation ----------
// S^T = K*Q'^T (Q pre-scaled by scale*log2e); p = exp2(S^T) lane-local;
// O^T = V^T * P; no max-tracking (scores bounded ~|6|), l reduced once at end.
__global__ __launch_bounds__(256, 4) void attn_k(const short* __restrict__ Qh,
                                                 const short* __restrict__ Kh,
                                                 const short* __restrict__ Vt,
                                                 const float* __restrict__ gates,
                                                 const float* __restrict__ meanV,
                                                 short* __restrict__ attnb) {
  const int bh = blockIdx.x;
  const int b = bh >> 4, h = bh & 15;
  const int q0 = blockIdx.y << 6;
  const int tid = threadIdx.x;
  const int w = tid >> 6, lane = tid & 63;
  const int m15 = lane & 15, quad = lane >> 4;

  __shared__ short Ks[2][4096];  // [64 k][64 d], 8-short blocks XOR-swizzled by row&7
  __shared__ short Vs[2][4096];  // [64 d][64 t], same swizzle

  const short* ksrc = Kh + bh * 65536;
  const short* vsrc = Vt + bh * 65536;

  // hoisted Q B-fragments (wave's 16 q-cols, loop-invariant)
  const short* qsrc = Qh + ((bh << 10) + q0 + (w << 4) + m15) * 64;
  const bf16x8 qb0 = *(const bf16x8*)(qsrc + (quad << 3));
  const bf16x8 qb1 = *(const bf16x8*)(qsrc + 32 + (quad << 3));

  // staging addresses (lane-linear LDS dest as global_load_lds requires)
  const int off0 = tid, off1 = tid + 256;
  const int r0 = off0 >> 3, cb0 = (off0 & 7) ^ (r0 & 7);
  const int r1 = off1 >> 3, cb1 = (off1 & 7) ^ (r1 & 7);

#define STAGE(kv, bufi)                                                        \
  do {                                                                         \
    async16(ksrc + (((kv) << 6) + r0) * 64 + (cb0 << 3), &Ks[bufi][off0 << 3]);\
    async16(ksrc + (((kv) << 6) + r1) * 64 + (cb1 << 3), &Ks[bufi][off1 << 3]);\
    async16(vsrc + r0 * 1024 + ((kv) << 6) + (cb0 << 3), &Vs[bufi][off0 << 3]);\
    async16(vsrc + r1 * 1024 + ((kv) << 6) + (cb1 << 3), &Vs[bufi][off1 << 3]);\
  } while (0)

  STAGE(0, 0);

  float lsum = 0.f;
  f32x4 o_acc[4];
#pragma unroll
  for (int jd = 0; jd < 4; ++jd) { f32x4 zz = {0.f, 0.f, 0.f, 0.f}; o_acc[jd] = zz; }

  const int srcA = ((quad & 1) << 5) + m15;  // source quad 2*(qt&1)
  const int srcB = srcA + 16;                // source quad 2*(qt&1)+1
  const bool selhi = (quad & 2) != 0;        // s = 2H + (quad>>1)

  for (int kv = 0; kv < 16; ++kv) {
    __syncthreads();  // drains STAGE(kv) (vmcnt) and prior iter's frag reads
    if (kv < 15) STAGE(kv + 1, (kv + 1) & 1);
    const short* Kb = &Ks[kv & 1][0];
    const short* Vb = &Vs[kv & 1][0];

    // S^T tile: lane holds (q = w*16+m15, k = kv*64 + s*16 + quad*4 + r)
    f32x4 sacc[4];
#pragma unroll
    for (int s = 0; s < 4; ++s) {
      const int row = (s << 4) + m15;
      const int sw = row & 7;
      bf16x8 a0 = *(const bf16x8*)(Kb + (row << 6) + ((quad ^ sw) << 3));
      bf16x8 a1 = *(const bf16x8*)(Kb + (row << 6) + (((quad + 4) ^ sw) << 3));
      f32x4 zz = {0.f, 0.f, 0.f, 0.f};
      zz = MFMA_BF16(a0, qb0, zz);
      zz = MFMA_BF16(a1, qb1, zz);
      sacc[s] = zz;
    }

    // lane-local softmax numerators + packed bf16 pairs
    uint32_t pk[4][2];
#pragma unroll
    for (int s = 0; s < 4; ++s) {
      float p0 = fexp2(sacc[s][0]);
      float p1 = fexp2(sacc[s][1]);
      float p2 = fexp2(sacc[s][2]);
      float p3 = fexp2(sacc[s][3]);
      lsum += (p0 + p1) + (p2 + p3);
      pk[s][0] = pack2bf(p0, p1);
      pk[s][1] = pack2bf(p2, p3);
    }

    // build P B-fragments: lane n=q needs k = H*32 + quad*8 + j
    bf16x8 pf[2];
#pragma unroll
    for (int H = 0; H < 2; ++H) {
      uint32_t f[4];
#pragma unroll
      for (int rp = 0; rp < 2; ++rp) {
        uint32_t alo = (uint32_t)__shfl((int)pk[2 * H][rp], srcA);
        uint32_t ahi = (uint32_t)__shfl((int)pk[2 * H + 1][rp], srcA);
        uint32_t blo = (uint32_t)__shfl((int)pk[2 * H][rp], srcB);
        uint32_t bhi = (uint32_t)__shfl((int)pk[2 * H + 1][rp], srcB);
        f[rp]     = selhi ? ahi : alo;
        f[2 + rp] = selhi ? bhi : blo;
      }
      pf[H] = *(bf16x8*)f;
    }

    // O^T += V^T * P
#pragma unroll
    for (int jd = 0; jd < 4; ++jd) {
      const int row = (jd << 4) + m15;
      const int sw = row & 7;
      bf16x8 v0 = *(const bf16x8*)(Vb + (row << 6) + ((quad ^ sw) << 3));
      bf16x8 v1 = *(const bf16x8*)(Vb + (row << 6) + (((quad + 4) ^ sw) << 3));
      o_acc[jd] = MFMA_BF16(v0, pf[0], o_acc[jd]);
      o_acc[jd] = MFMA_BF16(v1, pf[1], o_acc[jd]);
    }
  }
#undef STAGE

  // finish l(q): lane's partial covers its (quad,s,r) k-subset; reduce over quads
  float l = lsum;
  l += __shfl_xor(l, 16);
  l += __shfl_xor(l, 32);

  const float cg = gates[b * 2 + 0];
  const float s0 = cg / l;
  const float omc = 1.0f - cg;
  const int qrow = q0 + (w << 4) + m15;
  short* orow = attnb + ((b << 10) + qrow) * 1024 + (h << 6);
#pragma unroll
  for (int jd = 0; jd < 4; ++jd) {
    float4 mv = *(const float4*)(meanV + (bh << 6) + (jd << 4) + (quad << 2));
    float v0_ = s0 * o_acc[jd][0] + omc * mv.x;
    float v1_ = s0 * o_acc[jd][1] + omc * mv.y;
    float v2_ = s0 * o_acc[jd][2] + omc * mv.z;
    float v3_ = s0 * o_acc[jd][3] + omc * mv.w;
    uint2 st;
    st.x = pack2bf(v0_, v1_);
    st.y = pack2bf(v2_, v3_);
    *(uint2*)(orow + (jd << 4) + (quad << 2)) = st;
  }
}

// ---------- launch ----------
extern "C" void kernel_launch(void* const* d_in, const int* in_sizes, int n_in,
                              void* d_out, int out_size, void* d_ws, size_t ws_size,
                              hipStream_t stream) {
  const float* x   = (const float*)d_in[0];
  const float* Wq  = (const float*)d_in[1];
  const float* bq  = (const float*)d_in[2];
  const float* Wk  = (const float*)d_in[3];
  const float* bk  = (const float*)d_in[4];
  const float* Wv  = (const float*)d_in[5];
  const float* bv  = (const float*)d_in[6];
  const float* Wo  = (const float*)d_in[7];
  const float* bo  = (const float*)d_in[8];
  const float* Wg1 = (const float*)d_in[9];
  const float* bg1 = (const float*)d_in[10];
  const float* Wg2 = (const float*)d_in[11];
  const float* bg2 = (const float*)d_in[12];
  float* out = (float*)d_out;

  char* ws = (char*)d_ws;
  short* xb   = (short*)(ws + 0);          //  8 MB  x bf16 [4096][1024]
  short* Wqb  = (short*)(ws + 8388608);    //  2 MB
  short* Wkb  = (short*)(ws + 10485760);   //  2 MB
  short* Wvb  = (short*)(ws + 12582912);   //  2 MB
  short* Wob  = (short*)(ws + 14680064);   //  2 MB
  short* Qh   = (short*)(ws + 16777216);   //  8 MB  [BH][T][64]  (pre-scaled)
  short* Kh   = (short*)(ws + 25165824);   //  8 MB  [BH][T][64]
  short* Vt   = (short*)(ws + 33554432);   //  8 MB  [BH][64][T]
  short* attb = (short*)(ws + 41943040);   //  8 MB  [4096][1024]
  float* ctx  = (float*)(ws + 50331648);   // 16 KB
  float* gat  = (float*)(ws + 50348032);   // 32 B   [B][{c,scale}]
  float* mV   = (float*)(ws + 50348064);   // 16 KB  [BH][64]

  cvt_all<<<8192, 256, 0, stream>>>(x, Wq, Wk, Wv, Wo, xb, Wqb, Wkb, Wvb, Wob);

  gates_ctx<<<dim3(4, 16), 256, 0, stream>>>(x, Wq, bq, ctx);
  gates_fin<<<1, 256, 0, stream>>>(ctx, Wg1, bg1, Wg2, bg2, gat, out + 4194304);

  gemm_qkv<<<dim3(32, 8, 3), 256, 0, stream>>>(xb, Wqb, Wkb, Wvb, bq, bk, bv, gat, Qh, Kh, Vt);
  meanv_k<<<64, 256, 0, stream>>>(Vt, mV);
  attn_k<<<dim3(64, 16), 256, 0, stream>>>(Qh, Kh, Vt, gat, mV, attb);
  gemm_out<<<dim3(64, 8), 256, 0, stream>>>(attb, Wob, bo, out);
}

// Round 4
// 222.317 us; speedup vs baseline: 1.0243x; 1.0243x over previous
//
#include <hip/hip_runtime.h>
#include <stdint.h>

// ---------- types / helpers ----------
typedef short bf16x8 __attribute__((ext_vector_type(8)));
typedef float f32x4 __attribute__((ext_vector_type(4)));

#define MFMA_BF16(a, b, c) __builtin_amdgcn_mfma_f32_16x16x32_bf16((a), (b), (c), 0, 0, 0)

__device__ __forceinline__ short f2bf(float x) {
  union { float f; uint32_t u; } v; v.f = x;
  uint32_t r = (v.u + 0x7FFFu + ((v.u >> 16) & 1u)) >> 16;  // RNE
  return (short)r;
}
__device__ __forceinline__ uint32_t rnd_bf_hi(float x) {  // rounded bits, bf16 in high half
  union { float f; uint32_t u; } v; v.f = x;
  return v.u + 0x7FFFu + ((v.u >> 16) & 1u);
}
__device__ __forceinline__ uint32_t pack2bf(float a, float b) {
  // D = [bf16(b) : bf16(a)]  via byte-select
  return __builtin_amdgcn_perm(rnd_bf_hi(b), rnd_bf_hi(a), 0x07060302);
}
__device__ __forceinline__ float bfbits2f(uint32_t b16) {
  union { uint32_t u; float f; } v; v.u = b16 << 16; return v.f;
}
__device__ __forceinline__ float fexp2(float x) {
#if __has_builtin(__builtin_amdgcn_exp2f)
  return __builtin_amdgcn_exp2f(x);
#else
  return __expf(x * 0.6931471805599453f);
#endif
}
__device__ __forceinline__ void async16(const void* g, void* l) {
  __builtin_amdgcn_global_load_lds(
      (const __attribute__((address_space(1))) uint32_t*)g,
      (__attribute__((address_space(3))) uint32_t*)l, 16, 0, 0);
}

// ---------- fused fp32 -> bf16 casts (x + 4 weights, one launch) ----------
__global__ __launch_bounds__(256) void cvt_all(
    const float* __restrict__ x, const float* __restrict__ Wq,
    const float* __restrict__ Wk, const float* __restrict__ Wv,
    const float* __restrict__ Wo,
    short* __restrict__ xb, short* __restrict__ Wqb, short* __restrict__ Wkb,
    short* __restrict__ Wvb, short* __restrict__ Wob) {
  const int bid = blockIdx.x;
  const float* src; short* dst; int idx;
  if (bid < 4096) {
    src = x; dst = xb; idx = (bid << 8) + threadIdx.x;
  } else {
    const int r = bid - 4096;
    const int z = r >> 10;
    src = (z == 0) ? Wq : (z == 1) ? Wk : (z == 2) ? Wv : Wo;
    dst = (z == 0) ? Wqb : (z == 1) ? Wkb : (z == 2) ? Wvb : Wob;
    idx = ((r & 1023) << 8) + threadIdx.x;
  }
  float4 v = ((const float4*)src)[idx];
  short4 o;
  o.x = f2bf(v.x); o.y = f2bf(v.y); o.z = f2bf(v.z); o.w = f2bf(v.w);
  ((short4*)dst)[idx] = o;
}

// ---------- gates: context = x[b,0,:] @ Wq^T + bq (fp32, exact path) ----------
__global__ __launch_bounds__(256) void gates_ctx(const float* __restrict__ x,
                                                 const float* __restrict__ Wq,
                                                 const float* __restrict__ bq,
                                                 float* __restrict__ ctx) {
  const int b = blockIdx.x;         // 4
  const int n0 = blockIdx.y << 6;   // 16 blocks of 64 rows
  __shared__ float xs[1024];
  const int tid = threadIdx.x;
  for (int i = tid; i < 1024; i += 256) xs[i] = x[b * 1048576 + i];  // x[b,0,:]
  __syncthreads();
  const int w = tid >> 6, lane = tid & 63;
  const float4* xv4 = (const float4*)xs;
  for (int rr = 0; rr < 16; ++rr) {
    const int n = n0 + (w << 4) + rr;
    const float4* wrow = (const float4*)(Wq + n * 1024);
    float p = 0.f;
#pragma unroll
    for (int c2 = 0; c2 < 4; ++c2) {
      float4 wv = wrow[lane + (c2 << 6)];
      float4 xv = xv4[lane + (c2 << 6)];
      p += xv.x * wv.x + xv.y * wv.y + xv.z * wv.z + xv.w * wv.w;
    }
#pragma unroll
    for (int off = 32; off; off >>= 1) p += __shfl_xor(p, off);
    if (lane == 0) ctx[b * 1024 + n] = p + bq[n];
  }
}

// ---------- gates finisher: c, scale, u ----------
__global__ __launch_bounds__(256) void gates_fin(const float* __restrict__ ctx,
                                                 const float* __restrict__ Wg1,
                                                 const float* __restrict__ bg1,
                                                 const float* __restrict__ Wg2,
                                                 const float* __restrict__ bg2,
                                                 float* __restrict__ gates,
                                                 float* __restrict__ u_out) {
  __shared__ float red[16];
  const int tid = threadIdx.x, w = tid >> 6, lane = tid & 63;
  for (int b = 0; b < 4; ++b) {
    float4 cv = ((const float4*)(ctx + b * 1024))[tid];
    float4 w1 = ((const float4*)Wg1)[tid];
    float4 w2 = ((const float4*)Wg2)[tid];
    float p1 = cv.x * w1.x + cv.y * w1.y + cv.z * w1.z + cv.w * w1.w;
    float p2 = cv.x * w2.x + cv.y * w2.y + cv.z * w2.z + cv.w * w2.w;
#pragma unroll
    for (int off = 32; off; off >>= 1) { p1 += __shfl_xor(p1, off); p2 += __shfl_xor(p2, off); }
    if (lane == 0) { red[w] = p1; red[8 + w] = p2; }
    __syncthreads();
    if (tid == 0) {
      float g1 = red[0] + red[1] + red[2] + red[3] + bg1[0];
      float g2 = red[8] + red[9] + red[10] + red[11] + bg2[0];
      float q1 = 1.f / (1.f + expf(-g1));
      float q2 = 1.f / (1.f + expf(-g2));
      float c = fminf(fmaxf(q1 * q2, 1e-8f), 1.0f);
      gates[b * 2 + 0] = c;
      gates[b * 2 + 1] = (c < 0.3f ? c : 1.0f) * 0.125f;  // 1/(sqrt(64)*tau)
      u_out[b] = 1.0f - c;
    }
    __syncthreads();
  }
}

// ---------- QKV projection GEMM (m97 2-barrier K-loop — proven optimum here) ----------
// C[m,n] = sum_k xb[m,k]*W[n,k] + bias[n];  z=0:Q(scaled)  z=1:K  z=2:V^T [BH][64][T]
__global__ __launch_bounds__(256) void gemm_qkv(
    const short* __restrict__ xb,
    const short* __restrict__ Wqb, const short* __restrict__ Wkb, const short* __restrict__ Wvb,
    const float* __restrict__ bq, const float* __restrict__ bk, const float* __restrict__ bv,
    const float* __restrict__ gat,
    short* __restrict__ Qh, short* __restrict__ Kh, short* __restrict__ Vt) {
  const int z = blockIdx.z;
  const short* W = (z == 0) ? Wqb : (z == 1) ? Wkb : Wvb;
  const float* bias = (z == 0) ? bq : (z == 1) ? bk : bv;

  const int m0 = blockIdx.x << 7;
  const int n0 = blockIdx.y << 7;
  const int tid = threadIdx.x;
  const int w = tid >> 6, lane = tid & 63;
  const int m15 = lane & 15, quad = lane >> 4;
  const int wr = w >> 1, wc = w & 1;

  // Q pre-scale: scale * log2(e), block-uniform (128 rows never cross a batch)
  const float qsc = (z == 0) ? gat[(m0 >> 10) * 2 + 1] * 1.4426950408889634f : 1.0f;

  __shared__ short As[4096];
  __shared__ short Bs[4096];
  __shared__ short Ts2[8192];  // V-transpose scratch for waves 2,3 (As/Bs serve 0,1)

  f32x4 acc[4][4];
#pragma unroll
  for (int i = 0; i < 4; ++i)
#pragma unroll
    for (int j = 0; j < 4; ++j) { f32x4 zz = {0.f, 0.f, 0.f, 0.f}; acc[i][j] = zz; }

  const int srow = (w << 5) + (lane >> 2);
  const int scol = (lane & 3) << 3;
  const short* ga0 = xb + (m0 + srow) * 1024 + scol;
  const short* ga1 = ga0 + 16 * 1024;
  const short* gb0 = W + (n0 + srow) * 1024 + scol;
  const short* gb1 = gb0 + 16 * 1024;
  short* la0 = &As[srow * 32 + scol];
  short* la1 = la0 + 512;
  short* lb0 = &Bs[srow * 32 + scol];
  short* lb1 = lb0 + 512;

  for (int kt = 0; kt < 32; ++kt) {
    async16(ga0, la0); async16(ga1, la1);
    async16(gb0, lb0); async16(gb1, lb1);
    ga0 += 32; ga1 += 32; gb0 += 32; gb1 += 32;
    __syncthreads();
    bf16x8 a[4], b[4];
#pragma unroll
    for (int i = 0; i < 4; ++i)
      a[i] = *(const bf16x8*)(&As[((wr << 6) + (i << 4) + m15) * 32 + (quad << 3)]);
#pragma unroll
    for (int j = 0; j < 4; ++j)
      b[j] = *(const bf16x8*)(&Bs[((wc << 6) + (j << 4) + m15) * 32 + (quad << 3)]);
#pragma unroll
    for (int i = 0; i < 4; ++i)
#pragma unroll
      for (int j = 0; j < 4; ++j)
        acc[i][j] = MFMA_BF16(a[i], b[j], acc[i][j]);
    __syncthreads();
  }

  if (z == 2) {
    // V: per-wave 64x64 transpose in LDS (XOR-swizzled), coalesced 16B stores.
    // Last K-iter ends with a barrier, so staging LDS is reusable by waves 0,1.
    short* Ts = (w == 0) ? &As[0] : (w == 1) ? &Bs[0] : &Ts2[(w - 2) << 12];
    const int batch = m0 >> 10;
    const int tb0 = (m0 & 1023) + (wr << 6);
    const int h = (n0 >> 6) + wc;
#pragma unroll
    for (int j = 0; j < 4; ++j) {
      const int dkl = (j << 4) + m15;
      const float bb_ = bias[n0 + (wc << 6) + dkl];
#pragma unroll
      for (int i = 0; i < 4; ++i) {
        // t_local = (i<<4)+(quad<<2)+r ; block-of-8 = 2i+(quad>>1), within = (quad&1)*4+r
        uint2 pk;
        pk.x = pack2bf(acc[i][j][0] + bb_, acc[i][j][1] + bb_);
        pk.y = pack2bf(acc[i][j][2] + bb_, acc[i][j][3] + bb_);
        const int blk = (i << 1) + (quad >> 1);
        const int addr = (dkl << 6) + ((blk ^ (dkl & 7)) << 3) + ((quad & 1) << 2);
        *(uint2*)&Ts[addr] = pk;
      }
    }
    __syncthreads();
    const int tb = lane & 7, dr = lane >> 3;
#pragma unroll
    for (int it = 0; it < 8; ++it) {
      const int dkl = dr + (it << 3);
      const int addr = (dkl << 6) + ((tb ^ (dkl & 7)) << 3);
      uint4 vv = *(const uint4*)&Ts[addr];
      *(uint4*)(Vt + ((((batch << 4) + h) << 6) + dkl) * 1024 + tb0 + (tb << 3)) = vv;
    }
  } else {
#pragma unroll
    for (int j = 0; j < 4; ++j) {
      const int n = n0 + (wc << 6) + (j << 4) + m15;
      const float bb_ = bias[n];
      const int h = n >> 6, dk = n & 63;
#pragma unroll
      for (int i = 0; i < 4; ++i) {
        const int mb = m0 + (wr << 6) + (i << 4) + (quad << 2);
#pragma unroll
        for (int r = 0; r < 4; ++r) {
          const int m = mb + r;
          const int batch = m >> 10, t = m & 1023;
          const short o = f2bf((acc[i][j][r] + bb_) * qsc);
          if (z == 1) Kh[((batch * 16 + h) * 1024 + t) * 64 + dk] = o;
          else        Qh[((batch * 16 + h) * 1024 + t) * 64 + dk] = o;
        }
      }
    }
  }
}

// ---------- output projection GEMM: 64x128 tiles, m97 2-barrier, fp32 epilogue ----------
__global__ __launch_bounds__(256) void gemm_out(const short* __restrict__ Ab,
                                                const short* __restrict__ Wo,
                                                const float* __restrict__ bo,
                                                float* __restrict__ Cout) {
  const int m0 = blockIdx.x << 6;
  const int n0 = blockIdx.y << 7;
  const int tid = threadIdx.x;
  const int w = tid >> 6, lane = tid & 63;
  const int m15 = lane & 15, quad = lane >> 4;
  const int wr = w >> 1, wc = w & 1;

  __shared__ short As[2048];   // 64 x 32
  __shared__ short Bs[4096];   // 128 x 32

  f32x4 acc[2][4];
#pragma unroll
  for (int i = 0; i < 2; ++i)
#pragma unroll
    for (int j = 0; j < 4; ++j) { f32x4 zz = {0.f, 0.f, 0.f, 0.f}; acc[i][j] = zz; }

  const int arow = tid >> 2;                 // 64 rows, lane-linear lA = tid*8
  const int acol = (tid & 3) << 3;
  const short* gA = Ab + (m0 + arow) * 1024 + acol;
  short* lA = &As[arow * 32 + acol];

  const int srow = (w << 5) + (lane >> 2);   // B: same as qkv
  const int scol = (lane & 3) << 3;
  const short* gB0 = Wo + (n0 + srow) * 1024 + scol;
  const short* gB1 = gB0 + 16 * 1024;
  short* lB0 = &Bs[srow * 32 + scol];
  short* lB1 = lB0 + 512;

  for (int kt = 0; kt < 32; ++kt) {
    async16(gA, lA);
    async16(gB0, lB0); async16(gB1, lB1);
    gA += 32; gB0 += 32; gB1 += 32;
    __syncthreads();
    bf16x8 a[2], b[4];
#pragma unroll
    for (int i = 0; i < 2; ++i)
      a[i] = *(const bf16x8*)(&As[((wr << 5) + (i << 4) + m15) * 32 + (quad << 3)]);
#pragma unroll
    for (int j = 0; j < 4; ++j)
      b[j] = *(const bf16x8*)(&Bs[((wc << 6) + (j << 4) + m15) * 32 + (quad << 3)]);
#pragma unroll
    for (int i = 0; i < 2; ++i)
#pragma unroll
      for (int j = 0; j < 4; ++j)
        acc[i][j] = MFMA_BF16(a[i], b[j], acc[i][j]);
    __syncthreads();
  }

#pragma unroll
  for (int j = 0; j < 4; ++j) {
    const int n = n0 + (wc << 6) + (j << 4) + m15;
    const float bb_ = bo[n];
#pragma unroll
    for (int i = 0; i < 2; ++i) {
      const int mb = m0 + (wr << 5) + (i << 4) + (quad << 2);
#pragma unroll
      for (int r = 0; r < 4; ++r)
        Cout[(mb + r) * 1024 + n] = acc[i][j][r] + bb_;
    }
  }
}

// ---------- meanV over keys: meanV[bh][d] = mean_t Vt[bh][d][t] ----------
__global__ __launch_bounds__(256) void meanv_k(const short* __restrict__ Vt,
                                               float* __restrict__ meanV) {
  const int bh = blockIdx.x;
  const int tid = threadIdx.x;
  const int d = tid >> 2, part = tid & 3;
  const short* row = Vt + bh * 65536 + d * 1024 + part * 256;
  float s = 0.f;
#pragma unroll 4
  for (int i = 0; i < 64; ++i) {
    uint2 v = *(const uint2*)(row + i * 4);
    s += bfbits2f(v.x & 0xffffu) + bfbits2f(v.x >> 16) +
         bfbits2f(v.y & 0xffffu) + bfbits2f(v.y >> 16);
  }
  s += __shfl_xor(s, 1);
  s += __shfl_xor(s, 2);
  if (part == 0) meanV[bh * 64 + d] = s * (1.0f / 1024.0f);
}

// ---------- flash attention, transposed-S formulation ----------
// S^T = K*Q'^T (Q pre-scaled by scale*log2e); p = exp2(S^T) lane-local;
// O^T = V^T * P; no max-tracking (scores bounded ~|6|), l reduced once at end.
__global__ __launch_bounds__(256, 4) void attn_k(const short* __restrict__ Qh,
                                                 const short* __restrict__ Kh,
                                                 const short* __restrict__ Vt,
                                                 const float* __restrict__ gates,
                                                 const float* __restrict__ meanV,
                                                 short* __restrict__ attnb) {
  const int bh = blockIdx.x;
  const int b = bh >> 4, h = bh & 15;
  const int q0 = blockIdx.y << 6;
  const int tid = threadIdx.x;
  const int w = tid >> 6, lane = tid & 63;
  const int m15 = lane & 15, quad = lane >> 4;

  __shared__ short Ks[2][4096];  // [64 k][64 d], 8-short blocks XOR-swizzled by row&7
  __shared__ short Vs[2][4096];  // [64 d][64 t], same swizzle

  const short* ksrc = Kh + bh * 65536;
  const short* vsrc = Vt + bh * 65536;

  // hoisted Q B-fragments (wave's 16 q-cols, loop-invariant)
  const short* qsrc = Qh + ((bh << 10) + q0 + (w << 4) + m15) * 64;
  const bf16x8 qb0 = *(const bf16x8*)(qsrc + (quad << 3));
  const bf16x8 qb1 = *(const bf16x8*)(qsrc + 32 + (quad << 3));

  // staging addresses (lane-linear LDS dest as global_load_lds requires)
  const int off0 = tid, off1 = tid + 256;
  const int r0 = off0 >> 3, cb0 = (off0 & 7) ^ (r0 & 7);
  const int r1 = off1 >> 3, cb1 = (off1 & 7) ^ (r1 & 7);

#define STAGE(kv, bufi)                                                        \
  do {                                                                         \
    async16(ksrc + (((kv) << 6) + r0) * 64 + (cb0 << 3), &Ks[bufi][off0 << 3]);\
    async16(ksrc + (((kv) << 6) + r1) * 64 + (cb1 << 3), &Ks[bufi][off1 << 3]);\
    async16(vsrc + r0 * 1024 + ((kv) << 6) + (cb0 << 3), &Vs[bufi][off0 << 3]);\
    async16(vsrc + r1 * 1024 + ((kv) << 6) + (cb1 << 3), &Vs[bufi][off1 << 3]);\
  } while (0)

  STAGE(0, 0);

  float lsum = 0.f;
  f32x4 o_acc[4];
#pragma unroll
  for (int jd = 0; jd < 4; ++jd) { f32x4 zz = {0.f, 0.f, 0.f, 0.f}; o_acc[jd] = zz; }

  const int srcA = ((quad & 1) << 5) + m15;  // source quad 2*(qt&1)
  const int srcB = srcA + 16;                // source quad 2*(qt&1)+1
  const bool selhi = (quad & 2) != 0;        // s = 2H + (quad>>1)

  for (int kv = 0; kv < 16; ++kv) {
    __syncthreads();  // drains STAGE(kv) (vmcnt) and prior iter's frag reads
    if (kv < 15) STAGE(kv + 1, (kv + 1) & 1);
    const short* Kb = &Ks[kv & 1][0];
    const short* Vb = &Vs[kv & 1][0];

    // S^T tile: lane holds (q = w*16+m15, k = kv*64 + s*16 + quad*4 + r)
    f32x4 sacc[4];
#pragma unroll
    for (int s = 0; s < 4; ++s) {
      const int row = (s << 4) + m15;
      const int sw = row & 7;
      bf16x8 a0 = *(const bf16x8*)(Kb + (row << 6) + ((quad ^ sw) << 3));
      bf16x8 a1 = *(const bf16x8*)(Kb + (row << 6) + (((quad + 4) ^ sw) << 3));
      f32x4 zz = {0.f, 0.f, 0.f, 0.f};
      zz = MFMA_BF16(a0, qb0, zz);
      zz = MFMA_BF16(a1, qb1, zz);
      sacc[s] = zz;
    }

    // lane-local softmax numerators + packed bf16 pairs
    uint32_t pk[4][2];
#pragma unroll
    for (int s = 0; s < 4; ++s) {
      float p0 = fexp2(sacc[s][0]);
      float p1 = fexp2(sacc[s][1]);
      float p2 = fexp2(sacc[s][2]);
      float p3 = fexp2(sacc[s][3]);
      lsum += (p0 + p1) + (p2 + p3);
      pk[s][0] = pack2bf(p0, p1);
      pk[s][1] = pack2bf(p2, p3);
    }

    // build P B-fragments: lane n=q needs k = H*32 + quad*8 + j
    bf16x8 pf[2];
#pragma unroll
    for (int H = 0; H < 2; ++H) {
      uint32_t f[4];
#pragma unroll
      for (int rp = 0; rp < 2; ++rp) {
        uint32_t alo = (uint32_t)__shfl((int)pk[2 * H][rp], srcA);
        uint32_t ahi = (uint32_t)__shfl((int)pk[2 * H + 1][rp], srcA);
        uint32_t blo = (uint32_t)__shfl((int)pk[2 * H][rp], srcB);
        uint32_t bhi = (uint32_t)__shfl((int)pk[2 * H + 1][rp], srcB);
        f[rp]     = selhi ? ahi : alo;
        f[2 + rp] = selhi ? bhi : blo;
      }
      pf[H] = *(bf16x8*)f;
    }

    // O^T += V^T * P
#pragma unroll
    for (int jd = 0; jd < 4; ++jd) {
      const int row = (jd << 4) + m15;
      const int sw = row & 7;
      bf16x8 v0 = *(const bf16x8*)(Vb + (row << 6) + ((quad ^ sw) << 3));
      bf16x8 v1 = *(const bf16x8*)(Vb + (row << 6) + (((quad + 4) ^ sw) << 3));
      o_acc[jd] = MFMA_BF16(v0, pf[0], o_acc[jd]);
      o_acc[jd] = MFMA_BF16(v1, pf[1], o_acc[jd]);
    }
  }
#undef STAGE

  // finish l(q): lane's partial covers its (quad,s,r) k-subset; reduce over quads
  float l = lsum;
  l += __shfl_xor(l, 16);
  l += __shfl_xor(l, 32);

  const float cg = gates[b * 2 + 0];
  const float s0 = cg / l;
  const float omc = 1.0f - cg;
  const int qrow = q0 + (w << 4) + m15;
  short* orow = attnb + ((b << 10) + qrow) * 1024 + (h << 6);
#pragma unroll
  for (int jd = 0; jd < 4; ++jd) {
    float4 mv = *(const float4*)(meanV + (bh << 6) + (jd << 4) + (quad << 2));
    float v0_ = s0 * o_acc[jd][0] + omc * mv.x;
    float v1_ = s0 * o_acc[jd][1] + omc * mv.y;
    float v2_ = s0 * o_acc[jd][2] + omc * mv.z;
    float v3_ = s0 * o_acc[jd][3] + omc * mv.w;
    uint2 st;
    st.x = pack2bf(v0_, v1_);
    st.y = pack2bf(v2_, v3_);
    *(uint2*)(orow + (jd << 4) + (quad << 2)) = st;
  }
}

// ---------- launch ----------
extern "C" void kernel_launch(void* const* d_in, const int* in_sizes, int n_in,
                              void* d_out, int out_size, void* d_ws, size_t ws_size,
                              hipStream_t stream) {
  const float* x   = (const float*)d_in[0];
  const float* Wq  = (const float*)d_in[1];
  const float* bq  = (const float*)d_in[2];
  const float* Wk  = (const float*)d_in[3];
  const float* bk  = (const float*)d_in[4];
  const float* Wv  = (const float*)d_in[5];
  const float* bv  = (const float*)d_in[6];
  const float* Wo  = (const float*)d_in[7];
  const float* bo  = (const float*)d_in[8];
  const float* Wg1 = (const float*)d_in[9];
  const float* bg1 = (const float*)d_in[10];
  const float* Wg2 = (const float*)d_in[11];
  const float* bg2 = (const float*)d_in[12];
  float* out = (float*)d_out;

  char* ws = (char*)d_ws;
  short* xb   = (short*)(ws + 0);          //  8 MB  x bf16 [4096][1024]
  short* Wqb  = (short*)(ws + 8388608);    //  2 MB
  short* Wkb  = (short*)(ws + 10485760);   //  2 MB
  short* Wvb  = (short*)(ws + 12582912);   //  2 MB
  short* Wob  = (short*)(ws + 14680064);   //  2 MB
  short* Qh   = (short*)(ws + 16777216);   //  8 MB  [BH][T][64]  (pre-scaled)
  short* Kh   = (short*)(ws + 25165824);   //  8 MB  [BH][T][64]
  short* Vt   = (short*)(ws + 33554432);   //  8 MB  [BH][64][T]
  short* attb = (short*)(ws + 41943040);   //  8 MB  [4096][1024]
  float* ctx  = (float*)(ws + 50331648);   // 16 KB
  float* gat  = (float*)(ws + 50348032);   // 32 B   [B][{c,scale}]
  float* mV   = (float*)(ws + 50348064);   // 16 KB  [BH][64]

  cvt_all<<<8192, 256, 0, stream>>>(x, Wq, Wk, Wv, Wo, xb, Wqb, Wkb, Wvb, Wob);

  gates_ctx<<<dim3(4, 16), 256, 0, stream>>>(x, Wq, bq, ctx);
  gates_fin<<<1, 256, 0, stream>>>(ctx, Wg1, bg1, Wg2, bg2, gat, out + 4194304);

  gemm_qkv<<<dim3(32, 8, 3), 256, 0, stream>>>(xb, Wqb, Wkb, Wvb, bq, bk, bv, gat, Qh, Kh, Vt);
  meanv_k<<<64, 256, 0, stream>>>(Vt, mV);
  attn_k<<<dim3(64, 16), 256, 0, stream>>>(Qh, Kh, Vt, gat, mV, attb);
  gemm_out<<<dim3(64, 8), 256, 0, stream>>>(attb, Wob, bo, out);
}

// Round 5
// 218.558 us; speedup vs baseline: 1.0420x; 1.0172x over previous
//
#include <hip/hip_runtime.h>
#include <stdint.h>

// ---------- types / helpers ----------
typedef short bf16x8 __attribute__((ext_vector_type(8)));
typedef float f32x4 __attribute__((ext_vector_type(4)));

#define MFMA_BF16(a, b, c) __builtin_amdgcn_mfma_f32_16x16x32_bf16((a), (b), (c), 0, 0, 0)

__device__ __forceinline__ short f2bf(float x) {
  union { float f; uint32_t u; } v; v.f = x;
  uint32_t r = (v.u + 0x7FFFu + ((v.u >> 16) & 1u)) >> 16;  // RNE
  return (short)r;
}
__device__ __forceinline__ uint32_t rnd_bf_hi(float x) {  // rounded bits, bf16 in high half
  union { float f; uint32_t u; } v; v.f = x;
  return v.u + 0x7FFFu + ((v.u >> 16) & 1u);
}
__device__ __forceinline__ uint32_t pack2bf(float a, float b) {
  // D = [bf16(b) : bf16(a)]  via byte-select
  return __builtin_amdgcn_perm(rnd_bf_hi(b), rnd_bf_hi(a), 0x07060302);
}
__device__ __forceinline__ float bfbits2f(uint32_t b16) {
  union { uint32_t u; float f; } v; v.u = b16 << 16; return v.f;
}
__device__ __forceinline__ float fexp2(float x) {
#if __has_builtin(__builtin_amdgcn_exp2f)
  return __builtin_amdgcn_exp2f(x);
#else
  return __expf(x * 0.6931471805599453f);
#endif
}
__device__ __forceinline__ void async16(const void* g, void* l) {
  __builtin_amdgcn_global_load_lds(
      (const __attribute__((address_space(1))) uint32_t*)g,
      (__attribute__((address_space(3))) uint32_t*)l, 16, 0, 0);
}

// ---------- prep: fused fp32->bf16 casts + gates context GEMV ----------
__global__ __launch_bounds__(256) void prep_k(
    const float* __restrict__ x, const float* __restrict__ Wq,
    const float* __restrict__ Wk, const float* __restrict__ Wv,
    const float* __restrict__ Wo, const float* __restrict__ bq,
    short* __restrict__ xb, short* __restrict__ Wqb, short* __restrict__ Wkb,
    short* __restrict__ Wvb, short* __restrict__ Wob, float* __restrict__ ctx) {
  __shared__ float xs[1024];
  const int bid = blockIdx.x;
  const int tid = threadIdx.x;
  if (bid < 8192) {
    const float* src; short* dst; int idx;
    if (bid < 4096) {
      src = x; dst = xb; idx = (bid << 8) + tid;
    } else {
      const int r = bid - 4096;
      const int z = r >> 10;
      src = (z == 0) ? Wq : (z == 1) ? Wk : (z == 2) ? Wv : Wo;
      dst = (z == 0) ? Wqb : (z == 1) ? Wkb : (z == 2) ? Wvb : Wob;
      idx = ((r & 1023) << 8) + tid;
    }
    float4 v = ((const float4*)src)[idx];
    short4 o;
    o.x = f2bf(v.x); o.y = f2bf(v.y); o.z = f2bf(v.z); o.w = f2bf(v.w);
    ((short4*)dst)[idx] = o;
  } else {
    // gates context: ctx[b][n] = x[b,0,:] . Wq[n,:] + bq[n]   (fp32 exact path)
    const int r = bid - 8192;
    const int b = r >> 4;
    const int n0 = (r & 15) << 6;
    for (int i = tid; i < 1024; i += 256) xs[i] = x[b * 1048576 + i];
    __syncthreads();
    const int w = tid >> 6, lane = tid & 63;
    const float4* xv4 = (const float4*)xs;
    for (int rr = 0; rr < 16; ++rr) {
      const int n = n0 + (w << 4) + rr;
      const float4* wrow = (const float4*)(Wq + n * 1024);
      float p = 0.f;
#pragma unroll
      for (int c2 = 0; c2 < 4; ++c2) {
        float4 wv = wrow[lane + (c2 << 6)];
        float4 xv = xv4[lane + (c2 << 6)];
        p += xv.x * wv.x + xv.y * wv.y + xv.z * wv.z + xv.w * wv.w;
      }
#pragma unroll
      for (int off = 32; off; off >>= 1) p += __shfl_xor(p, off);
      if (lane == 0) ctx[b * 1024 + n] = p + bq[n];
    }
  }
}

// ---------- gates finisher: c, scale, u ----------
__global__ __launch_bounds__(256) void gates_fin(const float* __restrict__ ctx,
                                                 const float* __restrict__ Wg1,
                                                 const float* __restrict__ bg1,
                                                 const float* __restrict__ Wg2,
                                                 const float* __restrict__ bg2,
                                                 float* __restrict__ gates,
                                                 float* __restrict__ u_out) {
  __shared__ float red[16];
  const int tid = threadIdx.x, w = tid >> 6, lane = tid & 63;
  for (int b = 0; b < 4; ++b) {
    float4 cv = ((const float4*)(ctx + b * 1024))[tid];
    float4 w1 = ((const float4*)Wg1)[tid];
    float4 w2 = ((const float4*)Wg2)[tid];
    float p1 = cv.x * w1.x + cv.y * w1.y + cv.z * w1.z + cv.w * w1.w;
    float p2 = cv.x * w2.x + cv.y * w2.y + cv.z * w2.z + cv.w * w2.w;
#pragma unroll
    for (int off = 32; off; off >>= 1) { p1 += __shfl_xor(p1, off); p2 += __shfl_xor(p2, off); }
    if (lane == 0) { red[w] = p1; red[8 + w] = p2; }
    __syncthreads();
    if (tid == 0) {
      float g1 = red[0] + red[1] + red[2] + red[3] + bg1[0];
      float g2 = red[8] + red[9] + red[10] + red[11] + bg2[0];
      float q1 = 1.f / (1.f + expf(-g1));
      float q2 = 1.f / (1.f + expf(-g2));
      float c = fminf(fmaxf(q1 * q2, 1e-8f), 1.0f);
      gates[b * 2 + 0] = c;
      gates[b * 2 + 1] = (c < 0.3f ? c : 1.0f) * 0.125f;  // 1/(sqrt(64)*tau)
      u_out[b] = 1.0f - c;
    }
    __syncthreads();
  }
}

// ---------- QKV projection GEMM (m97 2-barrier K-loop, XOR-swizzled LDS) ----------
// Staging layout: As[row][32], physical col-block = logical ^ ((row>>1)&3).
// Bank group = 4*(row&1) + (quad ^ ((row>>1)&3)) -> 2-way only = free.
// C[m,n] = sum_k xb[m,k]*W[n,k] + bias[n];  z=0:Q(scaled)  z=1:K  z=2:V^T [BH][64][T]
__global__ __launch_bounds__(256) void gemm_qkv(
    const short* __restrict__ xb,
    const short* __restrict__ Wqb, const short* __restrict__ Wkb, const short* __restrict__ Wvb,
    const float* __restrict__ bq, const float* __restrict__ bk, const float* __restrict__ bv,
    const float* __restrict__ gat,
    short* __restrict__ Qh, short* __restrict__ Kh, short* __restrict__ Vt) {
  const int z = blockIdx.z;
  const short* W = (z == 0) ? Wqb : (z == 1) ? Wkb : Wvb;
  const float* bias = (z == 0) ? bq : (z == 1) ? bk : bv;

  const int m0 = blockIdx.x << 7;
  const int n0 = blockIdx.y << 7;
  const int tid = threadIdx.x;
  const int w = tid >> 6, lane = tid & 63;
  const int m15 = lane & 15, quad = lane >> 4;
  const int wr = w >> 1, wc = w & 1;

  // Q pre-scale: scale * log2(e), block-uniform (128 rows never cross a batch)
  const float qsc = (z == 0) ? gat[(m0 >> 10) * 2 + 1] * 1.4426950408889634f : 1.0f;

  __shared__ short As[4096];
  __shared__ short Bs[4096];

  f32x4 acc[4][4];
#pragma unroll
  for (int i = 0; i < 4; ++i)
#pragma unroll
    for (int j = 0; j < 4; ++j) { f32x4 zz = {0.f, 0.f, 0.f, 0.f}; acc[i][j] = zz; }

  // staging: slot s covers (row = s>>2, physical cb = s&3); fetch logical cb
  const int s0 = tid, s1 = tid + 256;
  const int row0 = s0 >> 2, lcb0 = (s0 & 3) ^ ((row0 >> 1) & 3);
  const int row1 = s1 >> 2, lcb1 = (s1 & 3) ^ ((row1 >> 1) & 3);
  const short* ga0 = xb + (m0 + row0) * 1024 + (lcb0 << 3);
  const short* ga1 = xb + (m0 + row1) * 1024 + (lcb1 << 3);
  const short* gb0 = W + (n0 + row0) * 1024 + (lcb0 << 3);
  const short* gb1 = W + (n0 + row1) * 1024 + (lcb1 << 3);
  short* la0 = &As[s0 << 3];
  short* la1 = &As[s1 << 3];
  short* lb0 = &Bs[s0 << 3];
  short* lb1 = &Bs[s1 << 3];

  for (int kt = 0; kt < 32; ++kt) {
    async16(ga0, la0); async16(ga1, la1);
    async16(gb0, lb0); async16(gb1, lb1);
    ga0 += 32; ga1 += 32; gb0 += 32; gb1 += 32;
    __syncthreads();
    bf16x8 a[4], b[4];
#pragma unroll
    for (int i = 0; i < 4; ++i) {
      const int ra = (wr << 6) + (i << 4) + m15;
      a[i] = *(const bf16x8*)(&As[ra * 32 + ((quad ^ ((ra >> 1) & 3)) << 3)]);
    }
#pragma unroll
    for (int j = 0; j < 4; ++j) {
      const int rb = (wc << 6) + (j << 4) + m15;
      b[j] = *(const bf16x8*)(&Bs[rb * 32 + ((quad ^ ((rb >> 1) & 3)) << 3)]);
    }
#pragma unroll
    for (int i = 0; i < 4; ++i)
#pragma unroll
      for (int j = 0; j < 4; ++j)
        acc[i][j] = MFMA_BF16(a[i], b[j], acc[i][j]);
    __syncthreads();
  }

  if (z == 2) {
    // V^T scatter: per (i,j) one packed 8B store (4 consecutive t at fixed dk)
    const int batch = m0 >> 10;
#pragma unroll
    for (int j = 0; j < 4; ++j) {
      const int n = n0 + (wc << 6) + (j << 4) + m15;
      const float bb_ = bias[n];
      const int h = n >> 6, dk = n & 63;
      short* vrow = Vt + ((((batch << 4) + h) << 6) + dk) * 1024;
#pragma unroll
      for (int i = 0; i < 4; ++i) {
        const int t = (m0 & 1023) + (wr << 6) + (i << 4) + (quad << 2);
        uint2 pk;
        pk.x = pack2bf(acc[i][j][0] + bb_, acc[i][j][1] + bb_);
        pk.y = pack2bf(acc[i][j][2] + bb_, acc[i][j][3] + bb_);
        *(uint2*)(vrow + t) = pk;
      }
    }
  } else {
#pragma unroll
    for (int j = 0; j < 4; ++j) {
      const int n = n0 + (wc << 6) + (j << 4) + m15;
      const float bb_ = bias[n];
      const int h = n >> 6, dk = n & 63;
#pragma unroll
      for (int i = 0; i < 4; ++i) {
        const int mb = m0 + (wr << 6) + (i << 4) + (quad << 2);
#pragma unroll
        for (int r = 0; r < 4; ++r) {
          const int m = mb + r;
          const int batch = m >> 10, t = m & 1023;
          const short o = f2bf((acc[i][j][r] + bb_) * qsc);
          if (z == 1) Kh[((batch * 16 + h) * 1024 + t) * 64 + dk] = o;
          else        Qh[((batch * 16 + h) * 1024 + t) * 64 + dk] = o;
        }
      }
    }
  }
}

// ---------- output projection GEMM: 64x128, m97 2-barrier, swizzled, fp32 out ----------
__global__ __launch_bounds__(256) void gemm_out(const short* __restrict__ Ab,
                                                const short* __restrict__ Wo,
                                                const float* __restrict__ bo,
                                                float* __restrict__ Cout) {
  const int m0 = blockIdx.x << 6;
  const int n0 = blockIdx.y << 7;
  const int tid = threadIdx.x;
  const int w = tid >> 6, lane = tid & 63;
  const int m15 = lane & 15, quad = lane >> 4;
  const int wr = w >> 1, wc = w & 1;

  __shared__ short As[2048];   // 64 x 32, swizzled
  __shared__ short Bs[4096];   // 128 x 32, swizzled

  f32x4 acc[2][4];
#pragma unroll
  for (int i = 0; i < 2; ++i)
#pragma unroll
    for (int j = 0; j < 4; ++j) { f32x4 zz = {0.f, 0.f, 0.f, 0.f}; acc[i][j] = zz; }

  const int s0 = tid, s1 = tid + 256;
  const int arow = s0 >> 2, alcb = (s0 & 3) ^ ((arow >> 1) & 3);
  const int brow0 = s0 >> 2, blcb0 = alcb;
  const int brow1 = s1 >> 2, blcb1 = (s1 & 3) ^ ((brow1 >> 1) & 3);
  const short* gA  = Ab + (m0 + arow) * 1024 + (alcb << 3);
  const short* gB0 = Wo + (n0 + brow0) * 1024 + (blcb0 << 3);
  const short* gB1 = Wo + (n0 + brow1) * 1024 + (blcb1 << 3);
  short* lA  = &As[s0 << 3];
  short* lB0 = &Bs[s0 << 3];
  short* lB1 = &Bs[s1 << 3];

  for (int kt = 0; kt < 32; ++kt) {
    async16(gA, lA);
    async16(gB0, lB0); async16(gB1, lB1);
    gA += 32; gB0 += 32; gB1 += 32;
    __syncthreads();
    bf16x8 a[2], b[4];
#pragma unroll
    for (int i = 0; i < 2; ++i) {
      const int ra = (wr << 5) + (i << 4) + m15;
      a[i] = *(const bf16x8*)(&As[ra * 32 + ((quad ^ ((ra >> 1) & 3)) << 3)]);
    }
#pragma unroll
    for (int j = 0; j < 4; ++j) {
      const int rb = (wc << 6) + (j << 4) + m15;
      b[j] = *(const bf16x8*)(&Bs[rb * 32 + ((quad ^ ((rb >> 1) & 3)) << 3)]);
    }
#pragma unroll
    for (int i = 0; i < 2; ++i)
#pragma unroll
      for (int j = 0; j < 4; ++j)
        acc[i][j] = MFMA_BF16(a[i], b[j], acc[i][j]);
    __syncthreads();
  }

#pragma unroll
  for (int j = 0; j < 4; ++j) {
    const int n = n0 + (wc << 6) + (j << 4) + m15;
    const float bb_ = bo[n];
#pragma unroll
    for (int i = 0; i < 2; ++i) {
      const int mb = m0 + (wr << 5) + (i << 4) + (quad << 2);
#pragma unroll
      for (int r = 0; r < 4; ++r)
        Cout[(mb + r) * 1024 + n] = acc[i][j][r] + bb_;
    }
  }
}

// ---------- meanV over keys: meanV[bh][d] = mean_t Vt[bh][d][t] ----------
__global__ __launch_bounds__(256) void meanv_k(const short* __restrict__ Vt,
                                               float* __restrict__ meanV) {
  const int bh = blockIdx.x;
  const int tid = threadIdx.x;
  const int d = tid >> 2, part = tid & 3;
  const short* row = Vt + bh * 65536 + d * 1024 + part * 256;
  float s = 0.f;
#pragma unroll 4
  for (int i = 0; i < 64; ++i) {
    uint2 v = *(const uint2*)(row + i * 4);
    s += bfbits2f(v.x & 0xffffu) + bfbits2f(v.x >> 16) +
         bfbits2f(v.y & 0xffffu) + bfbits2f(v.y >> 16);
  }
  s += __shfl_xor(s, 1);
  s += __shfl_xor(s, 2);
  if (part == 0) meanV[bh * 64 + d] = s * (1.0f / 1024.0f);
}

// ---------- flash attention, transposed-S formulation ----------
// S^T = K*Q'^T (Q pre-scaled by scale*log2e); p = exp2(S^T) lane-local;
// O^T = V^T * P; no max-tracking (scores bounded ~|6|), l reduced once at end.
__global__ __launch_bounds__(256, 4) void attn_k(const short* __restrict__ Qh,
                                                 const short* __restrict__ Kh,
                                                 const short* __restrict__ Vt,
                                                 const float* __restrict__ gates,
                                                 const float* __restrict__ meanV,
                                                 short* __restrict__ attnb) {
  const int bh = blockIdx.x;
  const int b = bh >> 4, h = bh & 15;
  const int q0 = blockIdx.y << 6;
  const int tid = threadIdx.x;
  const int w = tid >> 6, lane = tid & 63;
  const int m15 = lane & 15, quad = lane >> 4;

  __shared__ short Ks[2][4096];  // [64 k][64 d], 8-short blocks XOR-swizzled by row&7
  __shared__ short Vs[2][4096];  // [64 d][64 t], same swizzle

  const short* ksrc = Kh + bh * 65536;
  const short* vsrc = Vt + bh * 65536;

  // hoisted Q B-fragments (wave's 16 q-cols, loop-invariant)
  const short* qsrc = Qh + ((bh << 10) + q0 + (w << 4) + m15) * 64;
  const bf16x8 qb0 = *(const bf16x8*)(qsrc + (quad << 3));
  const bf16x8 qb1 = *(const bf16x8*)(qsrc + 32 + (quad << 3));

  // staging addresses (lane-linear LDS dest as global_load_lds requires)
  const int off0 = tid, off1 = tid + 256;
  const int r0 = off0 >> 3, cb0 = (off0 & 7) ^ (r0 & 7);
  const int r1 = off1 >> 3, cb1 = (off1 & 7) ^ (r1 & 7);

#define STAGE(kv, bufi)                                                        \
  do {                                                                         \
    async16(ksrc + (((kv) << 6) + r0) * 64 + (cb0 << 3), &Ks[bufi][off0 << 3]);\
    async16(ksrc + (((kv) << 6) + r1) * 64 + (cb1 << 3), &Ks[bufi][off1 << 3]);\
    async16(vsrc + r0 * 1024 + ((kv) << 6) + (cb0 << 3), &Vs[bufi][off0 << 3]);\
    async16(vsrc + r1 * 1024 + ((kv) << 6) + (cb1 << 3), &Vs[bufi][off1 << 3]);\
  } while (0)

  STAGE(0, 0);

  float lsum = 0.f;
  f32x4 o_acc[4];
#pragma unroll
  for (int jd = 0; jd < 4; ++jd) { f32x4 zz = {0.f, 0.f, 0.f, 0.f}; o_acc[jd] = zz; }

  const int srcA = ((quad & 1) << 5) + m15;  // source quad 2*(qt&1)
  const int srcB = srcA + 16;                // source quad 2*(qt&1)+1
  const bool selhi = (quad & 2) != 0;        // s = 2H + (quad>>1)

  for (int kv = 0; kv < 16; ++kv) {
    __syncthreads();  // drains STAGE(kv) (vmcnt) and prior iter's frag reads
    if (kv < 15) STAGE(kv + 1, (kv + 1) & 1);
    const short* Kb = &Ks[kv & 1][0];
    const short* Vb = &Vs[kv & 1][0];

    // S^T tile: lane holds (q = w*16+m15, k = kv*64 + s*16 + quad*4 + r)
    f32x4 sacc[4];
#pragma unroll
    for (int s = 0; s < 4; ++s) {
      const int row = (s << 4) + m15;
      const int sw = row & 7;
      bf16x8 a0 = *(const bf16x8*)(Kb + (row << 6) + ((quad ^ sw) << 3));
      bf16x8 a1 = *(const bf16x8*)(Kb + (row << 6) + (((quad + 4) ^ sw) << 3));
      f32x4 zz = {0.f, 0.f, 0.f, 0.f};
      zz = MFMA_BF16(a0, qb0, zz);
      zz = MFMA_BF16(a1, qb1, zz);
      sacc[s] = zz;
    }

    // lane-local softmax numerators + packed bf16 pairs
    uint32_t pk[4][2];
#pragma unroll
    for (int s = 0; s < 4; ++s) {
      float p0 = fexp2(sacc[s][0]);
      float p1 = fexp2(sacc[s][1]);
      float p2 = fexp2(sacc[s][2]);
      float p3 = fexp2(sacc[s][3]);
      lsum += (p0 + p1) + (p2 + p3);
      pk[s][0] = pack2bf(p0, p1);
      pk[s][1] = pack2bf(p2, p3);
    }

    // build P B-fragments: lane n=q needs k = H*32 + quad*8 + j
    bf16x8 pf[2];
#pragma unroll
    for (int H = 0; H < 2; ++H) {
      uint32_t f[4];
#pragma unroll
      for (int rp = 0; rp < 2; ++rp) {
        uint32_t alo = (uint32_t)__shfl((int)pk[2 * H][rp], srcA);
        uint32_t ahi = (uint32_t)__shfl((int)pk[2 * H + 1][rp], srcA);
        uint32_t blo = (uint32_t)__shfl((int)pk[2 * H][rp], srcB);
        uint32_t bhi = (uint32_t)__shfl((int)pk[2 * H + 1][rp], srcB);
        f[rp]     = selhi ? ahi : alo;
        f[2 + rp] = selhi ? bhi : blo;
      }
      pf[H] = *(bf16x8*)f;
    }

    // O^T += V^T * P
#pragma unroll
    for (int jd = 0; jd < 4; ++jd) {
      const int row = (jd << 4) + m15;
      const int sw = row & 7;
      bf16x8 v0 = *(const bf16x8*)(Vb + (row << 6) + ((quad ^ sw) << 3));
      bf16x8 v1 = *(const bf16x8*)(Vb + (row << 6) + (((quad + 4) ^ sw) << 3));
      o_acc[jd] = MFMA_BF16(v0, pf[0], o_acc[jd]);
      o_acc[jd] = MFMA_BF16(v1, pf[1], o_acc[jd]);
    }
  }
#undef STAGE

  // finish l(q): lane's partial covers its (quad,s,r) k-subset; reduce over quads
  float l = lsum;
  l += __shfl_xor(l, 16);
  l += __shfl_xor(l, 32);

  const float cg = gates[b * 2 + 0];
  const float s0 = cg / l;
  const float omc = 1.0f - cg;
  const int qrow = q0 + (w << 4) + m15;
  short* orow = attnb + ((b << 10) + qrow) * 1024 + (h << 6);
#pragma unroll
  for (int jd = 0; jd < 4; ++jd) {
    float4 mv = *(const float4*)(meanV + (bh << 6) + (jd << 4) + (quad << 2));
    float v0_ = s0 * o_acc[jd][0] + omc * mv.x;
    float v1_ = s0 * o_acc[jd][1] + omc * mv.y;
    float v2_ = s0 * o_acc[jd][2] + omc * mv.z;
    float v3_ = s0 * o_acc[jd][3] + omc * mv.w;
    uint2 st;
    st.x = pack2bf(v0_, v1_);
    st.y = pack2bf(v2_, v3_);
    *(uint2*)(orow + (jd << 4) + (quad << 2)) = st;
  }
}

// ---------- launch ----------
extern "C" void kernel_launch(void* const* d_in, const int* in_sizes, int n_in,
                              void* d_out, int out_size, void* d_ws, size_t ws_size,
                              hipStream_t stream) {
  const float* x   = (const float*)d_in[0];
  const float* Wq  = (const float*)d_in[1];
  const float* bq  = (const float*)d_in[2];
  const float* Wk  = (const float*)d_in[3];
  const float* bk  = (const float*)d_in[4];
  const float* Wv  = (const float*)d_in[5];
  const float* bv  = (const float*)d_in[6];
  const float* Wo  = (const float*)d_in[7];
  const float* bo  = (const float*)d_in[8];
  const float* Wg1 = (const float*)d_in[9];
  const float* bg1 = (const float*)d_in[10];
  const float* Wg2 = (const float*)d_in[11];
  const float* bg2 = (const float*)d_in[12];
  float* out = (float*)d_out;

  char* ws = (char*)d_ws;
  short* xb   = (short*)(ws + 0);          //  8 MB  x bf16 [4096][1024]
  short* Wqb  = (short*)(ws + 8388608);    //  2 MB
  short* Wkb  = (short*)(ws + 10485760);   //  2 MB
  short* Wvb  = (short*)(ws + 12582912);   //  2 MB
  short* Wob  = (short*)(ws + 14680064);   //  2 MB
  short* Qh   = (short*)(ws + 16777216);   //  8 MB  [BH][T][64]  (pre-scaled)
  short* Kh   = (short*)(ws + 25165824);   //  8 MB  [BH][T][64]
  short* Vt   = (short*)(ws + 33554432);   //  8 MB  [BH][64][T]
  short* attb = (short*)(ws + 41943040);   //  8 MB  [4096][1024]
  float* ctx  = (float*)(ws + 50331648);   // 16 KB
  float* gat  = (float*)(ws + 50348032);   // 32 B   [B][{c,scale}]
  float* mV   = (float*)(ws + 50348064);   // 16 KB  [BH][64]

  prep_k<<<8256, 256, 0, stream>>>(x, Wq, Wk, Wv, Wo, bq,
                                   xb, Wqb, Wkb, Wvb, Wob, ctx);
  gates_fin<<<1, 256, 0, stream>>>(ctx, Wg1, bg1, Wg2, bg2, gat, out + 4194304);

  gemm_qkv<<<dim3(32, 8, 3), 256, 0, stream>>>(xb, Wqb, Wkb, Wvb, bq, bk, bv, gat, Qh, Kh, Vt);
  meanv_k<<<64, 256, 0, stream>>>(Vt, mV);
  attn_k<<<dim3(64, 16), 256, 0, stream>>>(Qh, Kh, Vt, gat, mV, attb);
  gemm_out<<<dim3(64, 8), 256, 0, stream>>>(attb, Wob, bo, out);
}

// Round 6
// 217.564 us; speedup vs baseline: 1.0467x; 1.0046x over previous
//
#include <hip/hip_runtime.h>
#include <stdint.h>

// ---------- types / helpers ----------
typedef short bf16x8 __attribute__((ext_vector_type(8)));
typedef float f32x4 __attribute__((ext_vector_type(4)));

#define MFMA_BF16(a, b, c) __builtin_amdgcn_mfma_f32_16x16x32_bf16((a), (b), (c), 0, 0, 0)

__device__ __forceinline__ short f2bf(float x) {
  union { float f; uint32_t u; } v; v.f = x;
  uint32_t r = (v.u + 0x7FFFu + ((v.u >> 16) & 1u)) >> 16;  // RNE
  return (short)r;
}
__device__ __forceinline__ uint32_t rnd_bf_hi(float x) {  // rounded bits, bf16 in high half
  union { float f; uint32_t u; } v; v.f = x;
  return v.u + 0x7FFFu + ((v.u >> 16) & 1u);
}
__device__ __forceinline__ uint32_t pack2bf(float a, float b) {
  // D = [bf16(b) : bf16(a)]  via byte-select
  return __builtin_amdgcn_perm(rnd_bf_hi(b), rnd_bf_hi(a), 0x07060302);
}
__device__ __forceinline__ float bfbits2f(uint32_t b16) {
  union { uint32_t u; float f; } v; v.u = b16 << 16; return v.f;
}
__device__ __forceinline__ float fexp2(float x) {
#if __has_builtin(__builtin_amdgcn_exp2f)
  return __builtin_amdgcn_exp2f(x);
#else
  return __expf(x * 0.6931471805599453f);
#endif
}
__device__ __forceinline__ void async16(const void* g, void* l) {
  __builtin_amdgcn_global_load_lds(
      (const __attribute__((address_space(1))) uint32_t*)g,
      (__attribute__((address_space(3))) uint32_t*)l, 16, 0, 0);
}

// ---------- prep: fused fp32->bf16 casts + gates context GEMV ----------
__global__ __launch_bounds__(256) void prep_k(
    const float* __restrict__ x, const float* __restrict__ Wq,
    const float* __restrict__ Wk, const float* __restrict__ Wv,
    const float* __restrict__ Wo, const float* __restrict__ bq,
    short* __restrict__ xb, short* __restrict__ Wqb, short* __restrict__ Wkb,
    short* __restrict__ Wvb, short* __restrict__ Wob, float* __restrict__ ctx) {
  __shared__ float xs[1024];
  const int bid = blockIdx.x;
  const int tid = threadIdx.x;
  if (bid < 8192) {
    const float* src; short* dst; int idx;
    if (bid < 4096) {
      src = x; dst = xb; idx = (bid << 8) + tid;
    } else {
      const int r = bid - 4096;
      const int z = r >> 10;
      src = (z == 0) ? Wq : (z == 1) ? Wk : (z == 2) ? Wv : Wo;
      dst = (z == 0) ? Wqb : (z == 1) ? Wkb : (z == 2) ? Wvb : Wob;
      idx = ((r & 1023) << 8) + tid;
    }
    float4 v = ((const float4*)src)[idx];
    short4 o;
    o.x = f2bf(v.x); o.y = f2bf(v.y); o.z = f2bf(v.z); o.w = f2bf(v.w);
    ((short4*)dst)[idx] = o;
  } else {
    // gates context: ctx[b][n] = x[b,0,:] . Wq[n,:] + bq[n]   (fp32 exact path)
    const int r = bid - 8192;
    const int b = r >> 4;
    const int n0 = (r & 15) << 6;
    for (int i = tid; i < 1024; i += 256) xs[i] = x[b * 1048576 + i];
    __syncthreads();
    const int w = tid >> 6, lane = tid & 63;
    const float4* xv4 = (const float4*)xs;
    for (int rr = 0; rr < 16; ++rr) {
      const int n = n0 + (w << 4) + rr;
      const float4* wrow = (const float4*)(Wq + n * 1024);
      float p = 0.f;
#pragma unroll
      for (int c2 = 0; c2 < 4; ++c2) {
        float4 wv = wrow[lane + (c2 << 6)];
        float4 xv = xv4[lane + (c2 << 6)];
        p += xv.x * wv.x + xv.y * wv.y + xv.z * wv.z + xv.w * wv.w;
      }
#pragma unroll
      for (int off = 32; off; off >>= 1) p += __shfl_xor(p, off);
      if (lane == 0) ctx[b * 1024 + n] = p + bq[n];
    }
  }
}

// ---------- gates finisher: c, scale*log2e, u ----------
__global__ __launch_bounds__(256) void gates_fin(const float* __restrict__ ctx,
                                                 const float* __restrict__ Wg1,
                                                 const float* __restrict__ bg1,
                                                 const float* __restrict__ Wg2,
                                                 const float* __restrict__ bg2,
                                                 float* __restrict__ gates,
                                                 float* __restrict__ u_out) {
  __shared__ float red[16];
  const int tid = threadIdx.x, w = tid >> 6, lane = tid & 63;
  for (int b = 0; b < 4; ++b) {
    float4 cv = ((const float4*)(ctx + b * 1024))[tid];
    float4 w1 = ((const float4*)Wg1)[tid];
    float4 w2 = ((const float4*)Wg2)[tid];
    float p1 = cv.x * w1.x + cv.y * w1.y + cv.z * w1.z + cv.w * w1.w;
    float p2 = cv.x * w2.x + cv.y * w2.y + cv.z * w2.z + cv.w * w2.w;
#pragma unroll
    for (int off = 32; off; off >>= 1) { p1 += __shfl_xor(p1, off); p2 += __shfl_xor(p2, off); }
    if (lane == 0) { red[w] = p1; red[8 + w] = p2; }
    __syncthreads();
    if (tid == 0) {
      float g1 = red[0] + red[1] + red[2] + red[3] + bg1[0];
      float g2 = red[8] + red[9] + red[10] + red[11] + bg2[0];
      float q1 = 1.f / (1.f + expf(-g1));
      float q2 = 1.f / (1.f + expf(-g2));
      float c = fminf(fmaxf(q1 * q2, 1e-8f), 1.0f);
      gates[b * 2 + 0] = c;
      // (1/(sqrt(64)*tau)) * log2(e), applied to raw scores inside attn
      gates[b * 2 + 1] = (c < 0.3f ? c : 1.0f) * 0.125f * 1.4426950408889634f;
      u_out[b] = 1.0f - c;
    }
    __syncthreads();
  }
}

// ---------- QKV projection GEMM: 64x128 tiles (6 blocks/CU), 2-barrier, swizzled ----------
// C[m,n] = sum_k xb[m,k]*W[n,k] + bias[n];  z=0:Q  z=1:K  z=2:V^T [BH][64][T] + meanV atomics
__global__ __launch_bounds__(256) void gemm_qkv(
    const short* __restrict__ xb,
    const short* __restrict__ Wqb, const short* __restrict__ Wkb, const short* __restrict__ Wvb,
    const float* __restrict__ bq, const float* __restrict__ bk, const float* __restrict__ bv,
    short* __restrict__ Qh, short* __restrict__ Kh, short* __restrict__ Vt,
    float* __restrict__ mV) {
  const int z = blockIdx.z;
  const short* W = (z == 0) ? Wqb : (z == 1) ? Wkb : Wvb;
  const float* bias = (z == 0) ? bq : (z == 1) ? bk : bv;

  const int m0 = blockIdx.x << 6;
  const int n0 = blockIdx.y << 7;
  const int tid = threadIdx.x;
  const int w = tid >> 6, lane = tid & 63;
  const int m15 = lane & 15, quad = lane >> 4;
  const int wr = w >> 1, wc = w & 1;

  __shared__ short As[2048];   // 64 x 32, XOR-swizzled (col-block ^= (row>>1)&3)
  __shared__ short Bs[4096];   // 128 x 32, same swizzle

  f32x4 acc[2][4];
#pragma unroll
  for (int i = 0; i < 2; ++i)
#pragma unroll
    for (int j = 0; j < 4; ++j) { f32x4 zz = {0.f, 0.f, 0.f, 0.f}; acc[i][j] = zz; }

  const int s0 = tid, s1 = tid + 256;
  const int arow = s0 >> 2, alcb = (s0 & 3) ^ ((arow >> 1) & 3);
  const int brow1 = s1 >> 2, blcb1 = (s1 & 3) ^ ((brow1 >> 1) & 3);
  const short* gA  = xb + (m0 + arow) * 1024 + (alcb << 3);
  const short* gB0 = W + (n0 + arow) * 1024 + (alcb << 3);
  const short* gB1 = W + (n0 + brow1) * 1024 + (blcb1 << 3);
  short* lA  = &As[s0 << 3];
  short* lB0 = &Bs[s0 << 3];
  short* lB1 = &Bs[s1 << 3];

  for (int kt = 0; kt < 32; ++kt) {
    async16(gA, lA);
    async16(gB0, lB0); async16(gB1, lB1);
    gA += 32; gB0 += 32; gB1 += 32;
    __syncthreads();
    bf16x8 a[2], b[4];
#pragma unroll
    for (int i = 0; i < 2; ++i) {
      const int ra = (wr << 5) + (i << 4) + m15;
      a[i] = *(const bf16x8*)(&As[ra * 32 + ((quad ^ ((ra >> 1) & 3)) << 3)]);
    }
#pragma unroll
    for (int j = 0; j < 4; ++j) {
      const int rb = (wc << 6) + (j << 4) + m15;
      b[j] = *(const bf16x8*)(&Bs[rb * 32 + ((quad ^ ((rb >> 1) & 3)) << 3)]);
    }
#pragma unroll
    for (int i = 0; i < 2; ++i)
#pragma unroll
      for (int j = 0; j < 4; ++j)
        acc[i][j] = MFMA_BF16(a[i], b[j], acc[i][j]);
    __syncthreads();
  }

  if (z == 2) {
    // V^T scatter (packed 8B: 4 consecutive t at fixed dk) + meanV partial atomics
    const int batch = m0 >> 10;
#pragma unroll
    for (int j = 0; j < 4; ++j) {
      const int n = n0 + (wc << 6) + (j << 4) + m15;
      const float bb_ = bias[n];
      const int h = n >> 6, dk = n & 63;
      short* vrow = Vt + ((((batch << 4) + h) << 6) + dk) * 1024;
      float msum = 8.0f * bb_;
#pragma unroll
      for (int i = 0; i < 2; ++i) {
        const int t = (m0 & 1023) + (wr << 5) + (i << 4) + (quad << 2);
        uint2 pk;
        pk.x = pack2bf(acc[i][j][0] + bb_, acc[i][j][1] + bb_);
        pk.y = pack2bf(acc[i][j][2] + bb_, acc[i][j][3] + bb_);
        *(uint2*)(vrow + t) = pk;
        msum += (acc[i][j][0] + acc[i][j][1]) + (acc[i][j][2] + acc[i][j][3]);
      }
      msum += __shfl_xor(msum, 16);
      msum += __shfl_xor(msum, 32);
      if (quad == 0) atomicAdd(&mV[(((batch << 4) + h) << 6) + dk], msum);
    }
  } else {
#pragma unroll
    for (int j = 0; j < 4; ++j) {
      const int n = n0 + (wc << 6) + (j << 4) + m15;
      const float bb_ = bias[n];
      const int h = n >> 6, dk = n & 63;
#pragma unroll
      for (int i = 0; i < 2; ++i) {
        const int mb = m0 + (wr << 5) + (i << 4) + (quad << 2);
#pragma unroll
        for (int r = 0; r < 4; ++r) {
          const int m = mb + r;
          const int batch = m >> 10, t = m & 1023;
          const short o = f2bf(acc[i][j][r] + bb_);
          if (z == 1) Kh[((batch * 16 + h) * 1024 + t) * 64 + dk] = o;
          else        Qh[((batch * 16 + h) * 1024 + t) * 64 + dk] = o;
        }
      }
    }
  }
}

// ---------- output projection GEMM: 64x128, m97 2-barrier, swizzled, fp32 out ----------
__global__ __launch_bounds__(256) void gemm_out(const short* __restrict__ Ab,
                                                const short* __restrict__ Wo,
                                                const float* __restrict__ bo,
                                                float* __restrict__ Cout) {
  const int m0 = blockIdx.x << 6;
  const int n0 = blockIdx.y << 7;
  const int tid = threadIdx.x;
  const int w = tid >> 6, lane = tid & 63;
  const int m15 = lane & 15, quad = lane >> 4;
  const int wr = w >> 1, wc = w & 1;

  __shared__ short As[2048];   // 64 x 32, swizzled
  __shared__ short Bs[4096];   // 128 x 32, swizzled

  f32x4 acc[2][4];
#pragma unroll
  for (int i = 0; i < 2; ++i)
#pragma unroll
    for (int j = 0; j < 4; ++j) { f32x4 zz = {0.f, 0.f, 0.f, 0.f}; acc[i][j] = zz; }

  const int s0 = tid, s1 = tid + 256;
  const int arow = s0 >> 2, alcb = (s0 & 3) ^ ((arow >> 1) & 3);
  const int brow1 = s1 >> 2, blcb1 = (s1 & 3) ^ ((brow1 >> 1) & 3);
  const short* gA  = Ab + (m0 + arow) * 1024 + (alcb << 3);
  const short* gB0 = Wo + (n0 + arow) * 1024 + (alcb << 3);
  const short* gB1 = Wo + (n0 + brow1) * 1024 + (blcb1 << 3);
  short* lA  = &As[s0 << 3];
  short* lB0 = &Bs[s0 << 3];
  short* lB1 = &Bs[s1 << 3];

  for (int kt = 0; kt < 32; ++kt) {
    async16(gA, lA);
    async16(gB0, lB0); async16(gB1, lB1);
    gA += 32; gB0 += 32; gB1 += 32;
    __syncthreads();
    bf16x8 a[2], b[4];
#pragma unroll
    for (int i = 0; i < 2; ++i) {
      const int ra = (wr << 5) + (i << 4) + m15;
      a[i] = *(const bf16x8*)(&As[ra * 32 + ((quad ^ ((ra >> 1) & 3)) << 3)]);
    }
#pragma unroll
    for (int j = 0; j < 4; ++j) {
      const int rb = (wc << 6) + (j << 4) + m15;
      b[j] = *(const bf16x8*)(&Bs[rb * 32 + ((quad ^ ((rb >> 1) & 3)) << 3)]);
    }
#pragma unroll
    for (int i = 0; i < 2; ++i)
#pragma unroll
      for (int j = 0; j < 4; ++j)
        acc[i][j] = MFMA_BF16(a[i], b[j], acc[i][j]);
    __syncthreads();
  }

#pragma unroll
  for (int j = 0; j < 4; ++j) {
    const int n = n0 + (wc << 6) + (j << 4) + m15;
    const float bb_ = bo[n];
#pragma unroll
    for (int i = 0; i < 2; ++i) {
      const int mb = m0 + (wr << 5) + (i << 4) + (quad << 2);
#pragma unroll
      for (int r = 0; r < 4; ++r)
        Cout[(mb + r) * 1024 + n] = acc[i][j][r] + bb_;
    }
  }
}

// ---------- flash attention, transposed-S formulation ----------
// S^T = K*Q'^T; p = exp2(S^T * sl) lane-local (sl = scale*log2e);
// O^T = V^T * P; no max-tracking (|S*sl| bounded ~8), l reduced once at end.
__global__ __launch_bounds__(256, 4) void attn_k(const short* __restrict__ Qh,
                                                 const short* __restrict__ Kh,
                                                 const short* __restrict__ Vt,
                                                 const float* __restrict__ gates,
                                                 const float* __restrict__ mV,
                                                 short* __restrict__ attnb) {
  const int bh = blockIdx.x;
  const int b = bh >> 4, h = bh & 15;
  const int q0 = blockIdx.y << 6;
  const int tid = threadIdx.x;
  const int w = tid >> 6, lane = tid & 63;
  const int m15 = lane & 15, quad = lane >> 4;

  __shared__ short Ks[2][4096];  // [64 k][64 d], 8-short blocks XOR-swizzled by row&7
  __shared__ short Vs[2][4096];  // [64 d][64 t], same swizzle

  const short* ksrc = Kh + bh * 65536;
  const short* vsrc = Vt + bh * 65536;

  const float sl = gates[b * 2 + 1];

  // hoisted Q B-fragments (wave's 16 q-cols, loop-invariant)
  const short* qsrc = Qh + ((bh << 10) + q0 + (w << 4) + m15) * 64;
  const bf16x8 qb0 = *(const bf16x8*)(qsrc + (quad << 3));
  const bf16x8 qb1 = *(const bf16x8*)(qsrc + 32 + (quad << 3));

  // staging addresses (lane-linear LDS dest as global_load_lds requires)
  const int off0 = tid, off1 = tid + 256;
  const int r0 = off0 >> 3, cb0 = (off0 & 7) ^ (r0 & 7);
  const int r1 = off1 >> 3, cb1 = (off1 & 7) ^ (r1 & 7);

#define STAGE(kv, bufi)                                                        \
  do {                                                                         \
    async16(ksrc + (((kv) << 6) + r0) * 64 + (cb0 << 3), &Ks[bufi][off0 << 3]);\
    async16(ksrc + (((kv) << 6) + r1) * 64 + (cb1 << 3), &Ks[bufi][off1 << 3]);\
    async16(vsrc + r0 * 1024 + ((kv) << 6) + (cb0 << 3), &Vs[bufi][off0 << 3]);\
    async16(vsrc + r1 * 1024 + ((kv) << 6) + (cb1 << 3), &Vs[bufi][off1 << 3]);\
  } while (0)

  STAGE(0, 0);

  float lsum = 0.f;
  f32x4 o_acc[4];
#pragma unroll
  for (int jd = 0; jd < 4; ++jd) { f32x4 zz = {0.f, 0.f, 0.f, 0.f}; o_acc[jd] = zz; }

  const int srcA = ((quad & 1) << 5) + m15;  // source quad 2*(qt&1)
  const int srcB = srcA + 16;                // source quad 2*(qt&1)+1
  const bool selhi = (quad & 2) != 0;        // s = 2H + (quad>>1)

  for (int kv = 0; kv < 16; ++kv) {
    __syncthreads();  // drains STAGE(kv) (vmcnt) and prior iter's frag reads
    if (kv < 15) STAGE(kv + 1, (kv + 1) & 1);
    const short* Kb = &Ks[kv & 1][0];
    const short* Vb = &Vs[kv & 1][0];

    // S^T tile: lane holds (q = w*16+m15, k = kv*64 + s*16 + quad*4 + r)
    f32x4 sacc[4];
#pragma unroll
    for (int s = 0; s < 4; ++s) {
      const int row = (s << 4) + m15;
      const int sw = row & 7;
      bf16x8 a0 = *(const bf16x8*)(Kb + (row << 6) + ((quad ^ sw) << 3));
      bf16x8 a1 = *(const bf16x8*)(Kb + (row << 6) + (((quad + 4) ^ sw) << 3));
      f32x4 zz = {0.f, 0.f, 0.f, 0.f};
      zz = MFMA_BF16(a0, qb0, zz);
      zz = MFMA_BF16(a1, qb1, zz);
      sacc[s] = zz;
    }

    // lane-local softmax numerators + packed bf16 pairs
    uint32_t pk[4][2];
#pragma unroll
    for (int s = 0; s < 4; ++s) {
      float p0 = fexp2(sacc[s][0] * sl);
      float p1 = fexp2(sacc[s][1] * sl);
      float p2 = fexp2(sacc[s][2] * sl);
      float p3 = fexp2(sacc[s][3] * sl);
      lsum += (p0 + p1) + (p2 + p3);
      pk[s][0] = pack2bf(p0, p1);
      pk[s][1] = pack2bf(p2, p3);
    }

    // build P B-fragments: lane n=q needs k = H*32 + quad*8 + j
    bf16x8 pf[2];
#pragma unroll
    for (int H = 0; H < 2; ++H) {
      uint32_t f[4];
#pragma unroll
      for (int rp = 0; rp < 2; ++rp) {
        uint32_t alo = (uint32_t)__shfl((int)pk[2 * H][rp], srcA);
        uint32_t ahi = (uint32_t)__shfl((int)pk[2 * H + 1][rp], srcA);
        uint32_t blo = (uint32_t)__shfl((int)pk[2 * H][rp], srcB);
        uint32_t bhi = (uint32_t)__shfl((int)pk[2 * H + 1][rp], srcB);
        f[rp]     = selhi ? ahi : alo;
        f[2 + rp] = selhi ? bhi : blo;
      }
      pf[H] = *(bf16x8*)f;
    }

    // O^T += V^T * P
#pragma unroll
    for (int jd = 0; jd < 4; ++jd) {
      const int row = (jd << 4) + m15;
      const int sw = row & 7;
      bf16x8 v0 = *(const bf16x8*)(Vb + (row << 6) + ((quad ^ sw) << 3));
      bf16x8 v1 = *(const bf16x8*)(Vb + (row << 6) + (((quad + 4) ^ sw) << 3));
      o_acc[jd] = MFMA_BF16(v0, pf[0], o_acc[jd]);
      o_acc[jd] = MFMA_BF16(v1, pf[1], o_acc[jd]);
    }
  }
#undef STAGE

  // finish l(q): lane's partial covers its (quad,s,r) k-subset; reduce over quads
  float l = lsum;
  l += __shfl_xor(l, 16);
  l += __shfl_xor(l, 32);

  const float cg = gates[b * 2 + 0];
  const float s0 = cg / l;
  const float coef = (1.0f - cg) * (1.0f / 1024.0f);  // mV holds raw sums over t
  const int qrow = q0 + (w << 4) + m15;
  short* orow = attnb + ((b << 10) + qrow) * 1024 + (h << 6);
#pragma unroll
  for (int jd = 0; jd < 4; ++jd) {
    float4 mv = *(const float4*)(mV + (bh << 6) + (jd << 4) + (quad << 2));
    float v0_ = s0 * o_acc[jd][0] + coef * mv.x;
    float v1_ = s0 * o_acc[jd][1] + coef * mv.y;
    float v2_ = s0 * o_acc[jd][2] + coef * mv.z;
    float v3_ = s0 * o_acc[jd][3] + coef * mv.w;
    uint2 st;
    st.x = pack2bf(v0_, v1_);
    st.y = pack2bf(v2_, v3_);
    *(uint2*)(orow + (jd << 4) + (quad << 2)) = st;
  }
}

// ---------- launch ----------
extern "C" void kernel_launch(void* const* d_in, const int* in_sizes, int n_in,
                              void* d_out, int out_size, void* d_ws, size_t ws_size,
                              hipStream_t stream) {
  const float* x   = (const float*)d_in[0];
  const float* Wq  = (const float*)d_in[1];
  const float* bq  = (const float*)d_in[2];
  const float* Wk  = (const float*)d_in[3];
  const float* bk  = (const float*)d_in[4];
  const float* Wv  = (const float*)d_in[5];
  const float* bv  = (const float*)d_in[6];
  const float* Wo  = (const float*)d_in[7];
  const float* bo  = (const float*)d_in[8];
  const float* Wg1 = (const float*)d_in[9];
  const float* bg1 = (const float*)d_in[10];
  const float* Wg2 = (const float*)d_in[11];
  const float* bg2 = (const float*)d_in[12];
  float* out = (float*)d_out;

  char* ws = (char*)d_ws;
  short* xb   = (short*)(ws + 0);          //  8 MB  x bf16 [4096][1024]
  short* Wqb  = (short*)(ws + 8388608);    //  2 MB
  short* Wkb  = (short*)(ws + 10485760);   //  2 MB
  short* Wvb  = (short*)(ws + 12582912);   //  2 MB
  short* Wob  = (short*)(ws + 14680064);   //  2 MB
  short* Qh   = (short*)(ws + 16777216);   //  8 MB  [BH][T][64]
  short* Kh   = (short*)(ws + 25165824);   //  8 MB  [BH][T][64]
  short* Vt   = (short*)(ws + 33554432);   //  8 MB  [BH][64][T]
  short* attb = (short*)(ws + 41943040);   //  8 MB  [4096][1024]
  float* ctx  = (float*)(ws + 50331648);   // 16 KB
  float* gat  = (float*)(ws + 50348032);   // 32 B   [B][{c, scale*log2e}]
  float* mV   = (float*)(ws + 50348064);   // 16 KB  [BH][64] raw sums (atomic)

  hipMemsetAsync(mV, 0, 64 * 64 * sizeof(float), stream);

  prep_k<<<8256, 256, 0, stream>>>(x, Wq, Wk, Wv, Wo, bq,
                                   xb, Wqb, Wkb, Wvb, Wob, ctx);
  gates_fin<<<1, 256, 0, stream>>>(ctx, Wg1, bg1, Wg2, bg2, gat, out + 4194304);

  gemm_qkv<<<dim3(64, 8, 3), 256, 0, stream>>>(xb, Wqb, Wkb, Wvb, bq, bk, bv,
                                               Qh, Kh, Vt, mV);
  attn_k<<<dim3(64, 16), 256, 0, stream>>>(Qh, Kh, Vt, gat, mV, attb);
  gemm_out<<<dim3(64, 8), 256, 0, stream>>>(attb, Wob, bo, out);
}

// Round 7
// 212.338 us; speedup vs baseline: 1.0725x; 1.0246x over previous
//
#include <hip/hip_runtime.h>
#include <stdint.h>

// ---------- types / helpers ----------
typedef short bf16x8 __attribute__((ext_vector_type(8)));
typedef float f32x4 __attribute__((ext_vector_type(4)));

#define MFMA_BF16(a, b, c) __builtin_amdgcn_mfma_f32_16x16x32_bf16((a), (b), (c), 0, 0, 0)

__device__ __forceinline__ short f2bf(float x) {
  union { float f; uint32_t u; } v; v.f = x;
  uint32_t r = (v.u + 0x7FFFu + ((v.u >> 16) & 1u)) >> 16;  // RNE
  return (short)r;
}
__device__ __forceinline__ uint32_t rnd_bf_hi(float x) {  // rounded bits, bf16 in high half
  union { float f; uint32_t u; } v; v.f = x;
  return v.u + 0x7FFFu + ((v.u >> 16) & 1u);
}
__device__ __forceinline__ uint32_t pack2bf(float a, float b) {
  // D = [bf16(b) : bf16(a)]  via byte-select
  return __builtin_amdgcn_perm(rnd_bf_hi(b), rnd_bf_hi(a), 0x07060302);
}
__device__ __forceinline__ float bfbits2f(uint32_t b16) {
  union { uint32_t u; float f; } v; v.u = b16 << 16; return v.f;
}
__device__ __forceinline__ float fexp2(float x) {
#if __has_builtin(__builtin_amdgcn_exp2f)
  return __builtin_amdgcn_exp2f(x);
#else
  return __expf(x * 0.6931471805599453f);
#endif
}
__device__ __forceinline__ void async16(const void* g, void* l) {
  __builtin_amdgcn_global_load_lds(
      (const __attribute__((address_space(1))) uint32_t*)g,
      (__attribute__((address_space(3))) uint32_t*)l, 16, 0, 0);
}

// ---------- prep: fused fp32->bf16 casts + gates context GEMV ----------
__global__ __launch_bounds__(256) void prep_k(
    const float* __restrict__ x, const float* __restrict__ Wq,
    const float* __restrict__ Wk, const float* __restrict__ Wv,
    const float* __restrict__ Wo, const float* __restrict__ bq,
    short* __restrict__ xb, short* __restrict__ Wqb, short* __restrict__ Wkb,
    short* __restrict__ Wvb, short* __restrict__ Wob, float* __restrict__ ctx) {
  __shared__ float xs[1024];
  const int bid = blockIdx.x;
  const int tid = threadIdx.x;
  if (bid < 8192) {
    const float* src; short* dst; int idx;
    if (bid < 4096) {
      src = x; dst = xb; idx = (bid << 8) + tid;
    } else {
      const int r = bid - 4096;
      const int z = r >> 10;
      src = (z == 0) ? Wq : (z == 1) ? Wk : (z == 2) ? Wv : Wo;
      dst = (z == 0) ? Wqb : (z == 1) ? Wkb : (z == 2) ? Wvb : Wob;
      idx = ((r & 1023) << 8) + tid;
    }
    float4 v = ((const float4*)src)[idx];
    short4 o;
    o.x = f2bf(v.x); o.y = f2bf(v.y); o.z = f2bf(v.z); o.w = f2bf(v.w);
    ((short4*)dst)[idx] = o;
  } else {
    // gates context: ctx[b][n] = x[b,0,:] . Wq[n,:] + bq[n]   (fp32 exact path)
    const int r = bid - 8192;
    const int b = r >> 4;
    const int n0 = (r & 15) << 6;
    for (int i = tid; i < 1024; i += 256) xs[i] = x[b * 1048576 + i];
    __syncthreads();
    const int w = tid >> 6, lane = tid & 63;
    const float4* xv4 = (const float4*)xs;
    for (int rr = 0; rr < 16; ++rr) {
      const int n = n0 + (w << 4) + rr;
      const float4* wrow = (const float4*)(Wq + n * 1024);
      float p = 0.f;
#pragma unroll
      for (int c2 = 0; c2 < 4; ++c2) {
        float4 wv = wrow[lane + (c2 << 6)];
        float4 xv = xv4[lane + (c2 << 6)];
        p += xv.x * wv.x + xv.y * wv.y + xv.z * wv.z + xv.w * wv.w;
      }
#pragma unroll
      for (int off = 32; off; off >>= 1) p += __shfl_xor(p, off);
      if (lane == 0) ctx[b * 1024 + n] = p + bq[n];
    }
  }
}

// ---------- gates finisher: c, scale*log2e, u ----------
__global__ __launch_bounds__(256) void gates_fin(const float* __restrict__ ctx,
                                                 const float* __restrict__ Wg1,
                                                 const float* __restrict__ bg1,
                                                 const float* __restrict__ Wg2,
                                                 const float* __restrict__ bg2,
                                                 float* __restrict__ gates,
                                                 float* __restrict__ u_out) {
  __shared__ float red[16];
  const int tid = threadIdx.x, w = tid >> 6, lane = tid & 63;
  for (int b = 0; b < 4; ++b) {
    float4 cv = ((const float4*)(ctx + b * 1024))[tid];
    float4 w1 = ((const float4*)Wg1)[tid];
    float4 w2 = ((const float4*)Wg2)[tid];
    float p1 = cv.x * w1.x + cv.y * w1.y + cv.z * w1.z + cv.w * w1.w;
    float p2 = cv.x * w2.x + cv.y * w2.y + cv.z * w2.z + cv.w * w2.w;
#pragma unroll
    for (int off = 32; off; off >>= 1) { p1 += __shfl_xor(p1, off); p2 += __shfl_xor(p2, off); }
    if (lane == 0) { red[w] = p1; red[8 + w] = p2; }
    __syncthreads();
    if (tid == 0) {
      float g1 = red[0] + red[1] + red[2] + red[3] + bg1[0];
      float g2 = red[8] + red[9] + red[10] + red[11] + bg2[0];
      float q1 = 1.f / (1.f + expf(-g1));
      float q2 = 1.f / (1.f + expf(-g2));
      float c = fminf(fmaxf(q1 * q2, 1e-8f), 1.0f);
      gates[b * 2 + 0] = c;
      // (1/(sqrt(64)*tau)) * log2(e), applied to raw scores inside attn
      gates[b * 2 + 1] = (c < 0.3f ? c : 1.0f) * 0.125f * 1.4426950408889634f;
      u_out[b] = 1.0f - c;
    }
    __syncthreads();
  }
}

// ---------- QKV projection GEMM: exact R2 structure (measured 43.2 us) ----------
// 128x128 tile, 2-barrier K-loop, non-swizzled LDS, scatter epilogues.
// C[m,n] = sum_k xb[m,k]*W[n,k] + bias[n];  z=0:Q  z=1:K  z=2:V^T [BH][64][T]
__global__ __launch_bounds__(256) void gemm_qkv(
    const short* __restrict__ xb,
    const short* __restrict__ Wqb, const short* __restrict__ Wkb, const short* __restrict__ Wvb,
    const float* __restrict__ bq, const float* __restrict__ bk, const float* __restrict__ bv,
    short* __restrict__ Qh, short* __restrict__ Kh, short* __restrict__ Vt) {
  const int z = blockIdx.z;
  const short* W = (z == 0) ? Wqb : (z == 1) ? Wkb : Wvb;
  const float* bias = (z == 0) ? bq : (z == 1) ? bk : bv;

  const int m0 = blockIdx.x << 7;
  const int n0 = blockIdx.y << 7;
  const int tid = threadIdx.x;
  const int w = tid >> 6, lane = tid & 63;
  const int m15 = lane & 15, quad = lane >> 4;
  const int wr = w >> 1, wc = w & 1;

  __shared__ short As[4096];
  __shared__ short Bs[4096];

  f32x4 acc[4][4];
#pragma unroll
  for (int i = 0; i < 4; ++i)
#pragma unroll
    for (int j = 0; j < 4; ++j) { f32x4 zz = {0.f, 0.f, 0.f, 0.f}; acc[i][j] = zz; }

  const int srow = (w << 5) + (lane >> 2);
  const int scol = (lane & 3) << 3;
  const short* ga0 = xb + (m0 + srow) * 1024 + scol;
  const short* ga1 = ga0 + 16 * 1024;
  const short* gb0 = W + (n0 + srow) * 1024 + scol;
  const short* gb1 = gb0 + 16 * 1024;
  short* la0 = &As[srow * 32 + scol];
  short* la1 = la0 + 512;
  short* lb0 = &Bs[srow * 32 + scol];
  short* lb1 = lb0 + 512;

  for (int kt = 0; kt < 32; ++kt) {
    async16(ga0, la0); async16(ga1, la1);
    async16(gb0, lb0); async16(gb1, lb1);
    ga0 += 32; ga1 += 32; gb0 += 32; gb1 += 32;
    __syncthreads();
    bf16x8 a[4], b[4];
#pragma unroll
    for (int i = 0; i < 4; ++i)
      a[i] = *(const bf16x8*)(&As[((wr << 6) + (i << 4) + m15) * 32 + (quad << 3)]);
#pragma unroll
    for (int j = 0; j < 4; ++j)
      b[j] = *(const bf16x8*)(&Bs[((wc << 6) + (j << 4) + m15) * 32 + (quad << 3)]);
#pragma unroll
    for (int i = 0; i < 4; ++i)
#pragma unroll
      for (int j = 0; j < 4; ++j)
        acc[i][j] = MFMA_BF16(a[i], b[j], acc[i][j]);
    __syncthreads();
  }

#pragma unroll
  for (int j = 0; j < 4; ++j) {
    const int n = n0 + (wc << 6) + (j << 4) + m15;
    const float bb_ = bias[n];
    const int h = n >> 6, dk = n & 63;
#pragma unroll
    for (int i = 0; i < 4; ++i) {
      const int mb = m0 + (wr << 6) + (i << 4) + (quad << 2);
#pragma unroll
      for (int r = 0; r < 4; ++r) {
        const int m = mb + r;
        const int batch = m >> 10, t = m & 1023;
        const short o = f2bf(acc[i][j][r] + bb_);
        if (z == 2) {
          Vt[((batch * 16 + h) * 64 + dk) * 1024 + t] = o;        // [BH][64][T]
        } else if (z == 1) {
          Kh[((batch * 16 + h) * 1024 + t) * 64 + dk] = o;        // [BH][T][64]
        } else {
          Qh[((batch * 16 + h) * 1024 + t) * 64 + dk] = o;
        }
      }
    }
  }
}

// ---------- output projection GEMM: 64x128, m97 2-barrier, swizzled, fp32 out ----------
__global__ __launch_bounds__(256) void gemm_out(const short* __restrict__ Ab,
                                                const short* __restrict__ Wo,
                                                const float* __restrict__ bo,
                                                float* __restrict__ Cout) {
  const int m0 = blockIdx.x << 6;
  const int n0 = blockIdx.y << 7;
  const int tid = threadIdx.x;
  const int w = tid >> 6, lane = tid & 63;
  const int m15 = lane & 15, quad = lane >> 4;
  const int wr = w >> 1, wc = w & 1;

  __shared__ short As[2048];   // 64 x 32, swizzled
  __shared__ short Bs[4096];   // 128 x 32, swizzled

  f32x4 acc[2][4];
#pragma unroll
  for (int i = 0; i < 2; ++i)
#pragma unroll
    for (int j = 0; j < 4; ++j) { f32x4 zz = {0.f, 0.f, 0.f, 0.f}; acc[i][j] = zz; }

  const int s0 = tid, s1 = tid + 256;
  const int arow = s0 >> 2, alcb = (s0 & 3) ^ ((arow >> 1) & 3);
  const int brow1 = s1 >> 2, blcb1 = (s1 & 3) ^ ((brow1 >> 1) & 3);
  const short* gA  = Ab + (m0 + arow) * 1024 + (alcb << 3);
  const short* gB0 = Wo + (n0 + arow) * 1024 + (alcb << 3);
  const short* gB1 = Wo + (n0 + brow1) * 1024 + (blcb1 << 3);
  short* lA  = &As[s0 << 3];
  short* lB0 = &Bs[s0 << 3];
  short* lB1 = &Bs[s1 << 3];

  for (int kt = 0; kt < 32; ++kt) {
    async16(gA, lA);
    async16(gB0, lB0); async16(gB1, lB1);
    gA += 32; gB0 += 32; gB1 += 32;
    __syncthreads();
    bf16x8 a[2], b[4];
#pragma unroll
    for (int i = 0; i < 2; ++i) {
      const int ra = (wr << 5) + (i << 4) + m15;
      a[i] = *(const bf16x8*)(&As[ra * 32 + ((quad ^ ((ra >> 1) & 3)) << 3)]);
    }
#pragma unroll
    for (int j = 0; j < 4; ++j) {
      const int rb = (wc << 6) + (j << 4) + m15;
      b[j] = *(const bf16x8*)(&Bs[rb * 32 + ((quad ^ ((rb >> 1) & 3)) << 3)]);
    }
#pragma unroll
    for (int i = 0; i < 2; ++i)
#pragma unroll
      for (int j = 0; j < 4; ++j)
        acc[i][j] = MFMA_BF16(a[i], b[j], acc[i][j]);
    __syncthreads();
  }

#pragma unroll
  for (int j = 0; j < 4; ++j) {
    const int n = n0 + (wc << 6) + (j << 4) + m15;
    const float bb_ = bo[n];
#pragma unroll
    for (int i = 0; i < 2; ++i) {
      const int mb = m0 + (wr << 5) + (i << 4) + (quad << 2);
#pragma unroll
      for (int r = 0; r < 4; ++r)
        Cout[(mb + r) * 1024 + n] = acc[i][j][r] + bb_;
    }
  }
}

// ---------- meanV over keys: mV[bh][d] = sum_t Vt[bh][d][t]  (raw sum) ----------
__global__ __launch_bounds__(256) void meanv_k(const short* __restrict__ Vt,
                                               float* __restrict__ mV) {
  const int bh = blockIdx.x;
  const int tid = threadIdx.x;
  const int d = tid >> 2, part = tid & 3;
  const short* row = Vt + bh * 65536 + d * 1024 + part * 256;
  float s = 0.f;
#pragma unroll 4
  for (int i = 0; i < 64; ++i) {
    uint2 v = *(const uint2*)(row + i * 4);
    s += bfbits2f(v.x & 0xffffu) + bfbits2f(v.x >> 16) +
         bfbits2f(v.y & 0xffffu) + bfbits2f(v.y >> 16);
  }
  s += __shfl_xor(s, 1);
  s += __shfl_xor(s, 2);
  if (part == 0) mV[bh * 64 + d] = s;
}

// ---------- flash attention, transposed-S formulation ----------
// S^T = K*Q'^T; p = exp2(S^T * sl) lane-local (sl = scale*log2e);
// O^T = V^T * P; no max-tracking (|S*sl| bounded ~8), l reduced once at end.
__global__ __launch_bounds__(256, 4) void attn_k(const short* __restrict__ Qh,
                                                 const short* __restrict__ Kh,
                                                 const short* __restrict__ Vt,
                                                 const float* __restrict__ gates,
                                                 const float* __restrict__ mV,
                                                 short* __restrict__ attnb) {
  const int bh = blockIdx.x;
  const int b = bh >> 4, h = bh & 15;
  const int q0 = blockIdx.y << 6;
  const int tid = threadIdx.x;
  const int w = tid >> 6, lane = tid & 63;
  const int m15 = lane & 15, quad = lane >> 4;

  __shared__ short Ks[2][4096];  // [64 k][64 d], 8-short blocks XOR-swizzled by row&7
  __shared__ short Vs[2][4096];  // [64 d][64 t], same swizzle

  const short* ksrc = Kh + bh * 65536;
  const short* vsrc = Vt + bh * 65536;

  const float sl = gates[b * 2 + 1];

  // hoisted Q B-fragments (wave's 16 q-cols, loop-invariant)
  const short* qsrc = Qh + ((bh << 10) + q0 + (w << 4) + m15) * 64;
  const bf16x8 qb0 = *(const bf16x8*)(qsrc + (quad << 3));
  const bf16x8 qb1 = *(const bf16x8*)(qsrc + 32 + (quad << 3));

  // staging addresses (lane-linear LDS dest as global_load_lds requires)
  const int off0 = tid, off1 = tid + 256;
  const int r0 = off0 >> 3, cb0 = (off0 & 7) ^ (r0 & 7);
  const int r1 = off1 >> 3, cb1 = (off1 & 7) ^ (r1 & 7);

#define STAGE(kv, bufi)                                                        \
  do {                                                                         \
    async16(ksrc + (((kv) << 6) + r0) * 64 + (cb0 << 3), &Ks[bufi][off0 << 3]);\
    async16(ksrc + (((kv) << 6) + r1) * 64 + (cb1 << 3), &Ks[bufi][off1 << 3]);\
    async16(vsrc + r0 * 1024 + ((kv) << 6) + (cb0 << 3), &Vs[bufi][off0 << 3]);\
    async16(vsrc + r1 * 1024 + ((kv) << 6) + (cb1 << 3), &Vs[bufi][off1 << 3]);\
  } while (0)

  STAGE(0, 0);

  float lsum = 0.f;
  f32x4 o_acc[4];
#pragma unroll
  for (int jd = 0; jd < 4; ++jd) { f32x4 zz = {0.f, 0.f, 0.f, 0.f}; o_acc[jd] = zz; }

  const int srcA = ((quad & 1) << 5) + m15;  // source quad 2*(qt&1)
  const int srcB = srcA + 16;                // source quad 2*(qt&1)+1
  const bool selhi = (quad & 2) != 0;        // s = 2H + (quad>>1)

  for (int kv = 0; kv < 16; ++kv) {
    __syncthreads();  // drains STAGE(kv) (vmcnt) and prior iter's frag reads
    if (kv < 15) STAGE(kv + 1, (kv + 1) & 1);
    const short* Kb = &Ks[kv & 1][0];
    const short* Vb = &Vs[kv & 1][0];

    // S^T tile: lane holds (q = w*16+m15, k = kv*64 + s*16 + quad*4 + r)
    f32x4 sacc[4];
#pragma unroll
    for (int s = 0; s < 4; ++s) {
      const int row = (s << 4) + m15;
      const int sw = row & 7;
      bf16x8 a0 = *(const bf16x8*)(Kb + (row << 6) + ((quad ^ sw) << 3));
      bf16x8 a1 = *(const bf16x8*)(Kb + (row << 6) + (((quad + 4) ^ sw) << 3));
      f32x4 zz = {0.f, 0.f, 0.f, 0.f};
      zz = MFMA_BF16(a0, qb0, zz);
      zz = MFMA_BF16(a1, qb1, zz);
      sacc[s] = zz;
    }

    // lane-local softmax numerators + packed bf16 pairs
    uint32_t pk[4][2];
#pragma unroll
    for (int s = 0; s < 4; ++s) {
      float p0 = fexp2(sacc[s][0] * sl);
      float p1 = fexp2(sacc[s][1] * sl);
      float p2 = fexp2(sacc[s][2] * sl);
      float p3 = fexp2(sacc[s][3] * sl);
      lsum += (p0 + p1) + (p2 + p3);
      pk[s][0] = pack2bf(p0, p1);
      pk[s][1] = pack2bf(p2, p3);
    }

    // build P B-fragments: lane n=q needs k = H*32 + quad*8 + j
    bf16x8 pf[2];
#pragma unroll
    for (int H = 0; H < 2; ++H) {
      uint32_t f[4];
#pragma unroll
      for (int rp = 0; rp < 2; ++rp) {
        uint32_t alo = (uint32_t)__shfl((int)pk[2 * H][rp], srcA);
        uint32_t ahi = (uint32_t)__shfl((int)pk[2 * H + 1][rp], srcA);
        uint32_t blo = (uint32_t)__shfl((int)pk[2 * H][rp], srcB);
        uint32_t bhi = (uint32_t)__shfl((int)pk[2 * H + 1][rp], srcB);
        f[rp]     = selhi ? ahi : alo;
        f[2 + rp] = selhi ? bhi : blo;
      }
      pf[H] = *(bf16x8*)f;
    }

    // O^T += V^T * P
#pragma unroll
    for (int jd = 0; jd < 4; ++jd) {
      const int row = (jd << 4) + m15;
      const int sw = row & 7;
      bf16x8 v0 = *(const bf16x8*)(Vb + (row << 6) + ((quad ^ sw) << 3));
      bf16x8 v1 = *(const bf16x8*)(Vb + (row << 6) + (((quad + 4) ^ sw) << 3));
      o_acc[jd] = MFMA_BF16(v0, pf[0], o_acc[jd]);
      o_acc[jd] = MFMA_BF16(v1, pf[1], o_acc[jd]);
    }
  }
#undef STAGE

  // finish l(q): lane's partial covers its (quad,s,r) k-subset; reduce over quads
  float l = lsum;
  l += __shfl_xor(l, 16);
  l += __shfl_xor(l, 32);

  const float cg = gates[b * 2 + 0];
  const float s0 = cg / l;
  const float coef = (1.0f - cg) * (1.0f / 1024.0f);  // mV holds raw sums over t
  const int qrow = q0 + (w << 4) + m15;
  short* orow = attnb + ((b << 10) + qrow) * 1024 + (h << 6);
#pragma unroll
  for (int jd = 0; jd < 4; ++jd) {
    float4 mv = *(const float4*)(mV + (bh << 6) + (jd << 4) + (quad << 2));
    float v0_ = s0 * o_acc[jd][0] + coef * mv.x;
    float v1_ = s0 * o_acc[jd][1] + coef * mv.y;
    float v2_ = s0 * o_acc[jd][2] + coef * mv.z;
    float v3_ = s0 * o_acc[jd][3] + coef * mv.w;
    uint2 st;
    st.x = pack2bf(v0_, v1_);
    st.y = pack2bf(v2_, v3_);
    *(uint2*)(orow + (jd << 4) + (quad << 2)) = st;
  }
}

// ---------- launch ----------
extern "C" void kernel_launch(void* const* d_in, const int* in_sizes, int n_in,
                              void* d_out, int out_size, void* d_ws, size_t ws_size,
                              hipStream_t stream) {
  const float* x   = (const float*)d_in[0];
  const float* Wq  = (const float*)d_in[1];
  const float* bq  = (const float*)d_in[2];
  const float* Wk  = (const float*)d_in[3];
  const float* bk  = (const float*)d_in[4];
  const float* Wv  = (const float*)d_in[5];
  const float* bv  = (const float*)d_in[6];
  const float* Wo  = (const float*)d_in[7];
  const float* bo  = (const float*)d_in[8];
  const float* Wg1 = (const float*)d_in[9];
  const float* bg1 = (const float*)d_in[10];
  const float* Wg2 = (const float*)d_in[11];
  const float* bg2 = (const float*)d_in[12];
  float* out = (float*)d_out;

  char* ws = (char*)d_ws;
  short* xb   = (short*)(ws + 0);          //  8 MB  x bf16 [4096][1024]
  short* Wqb  = (short*)(ws + 8388608);    //  2 MB
  short* Wkb  = (short*)(ws + 10485760);   //  2 MB
  short* Wvb  = (short*)(ws + 12582912);   //  2 MB
  short* Wob  = (short*)(ws + 14680064);   //  2 MB
  short* Qh   = (short*)(ws + 16777216);   //  8 MB  [BH][T][64]
  short* Kh   = (short*)(ws + 25165824);   //  8 MB  [BH][T][64]
  short* Vt   = (short*)(ws + 33554432);   //  8 MB  [BH][64][T]
  short* attb = (short*)(ws + 41943040);   //  8 MB  [4096][1024]
  float* ctx  = (float*)(ws + 50331648);   // 16 KB
  float* gat  = (float*)(ws + 50348032);   // 32 B   [B][{c, scale*log2e}]
  float* mV   = (float*)(ws + 50348064);   // 16 KB  [BH][64] raw sums

  prep_k<<<8256, 256, 0, stream>>>(x, Wq, Wk, Wv, Wo, bq,
                                   xb, Wqb, Wkb, Wvb, Wob, ctx);
  gates_fin<<<1, 256, 0, stream>>>(ctx, Wg1, bg1, Wg2, bg2, gat, out + 4194304);

  gemm_qkv<<<dim3(32, 8, 3), 256, 0, stream>>>(xb, Wqb, Wkb, Wvb, bq, bk, bv,
                                               Qh, Kh, Vt);
  meanv_k<<<64, 256, 0, stream>>>(Vt, mV);
  attn_k<<<dim3(64, 16), 256, 0, stream>>>(Qh, Kh, Vt, gat, mV, attb);
  gemm_out<<<dim3(64, 8), 256, 0, stream>>>(attb, Wob, bo, out);
}